// Round 12
// baseline (8821.410 us; speedup 1.0000x reference)
//
#include <hip/hip_runtime.h>
#include <math.h>

#define B_ 32
#define T_ 64
#define S_ 256
#define H_ 1024
#define E_ 512
#define BH_ (B_ * H_)

__device__ __forceinline__ float sigm(float x) {
    return 1.0f / (1.0f + __expf(-x));
}
__device__ __forceinline__ float tanh_(float x) {
    x = fminf(15.0f, fmaxf(-15.0f, x));
    float e = __expf(-2.0f * x);
    return (1.0f - e) / (1.0f + e);
}
// f32 -> bf16 round-to-nearest-even (finite inputs)
__device__ __forceinline__ unsigned short f2bf(float f) {
    unsigned int u = __float_as_uint(f);
    u = (u + 0x7fffu + ((u >> 16) & 1u)) >> 16;
    return (unsigned short)u;
}
// unpack one uint holding 2 bf16 (lo = even k, hi = odd k)
__device__ __forceinline__ float bflo(unsigned int u) { return __uint_as_float(u << 16); }
__device__ __forceinline__ float bfhi(unsigned int u) { return __uint_as_float(u & 0xffff0000u); }

// ---------------------------------------------------------------------------
// init: state ping-pong slot 0 + zero input feed
// ---------------------------------------------------------------------------
__global__ void k_init(const float* __restrict__ h0in, const float* __restrict__ c0in,
                       float* h0s, float* c0s, float* h1s, float* c1s, float* feed) {
    int i = blockIdx.x * 256 + threadIdx.x;
    if (i < BH_) {
        h0s[i]  = h0in[i];
        h1s[i]  = h0in[BH_ + i];
        c0s[i]  = c0in[i];
        c1s[i]  = c0in[BH_ + i];
        feed[i] = 0.0f;
    }
}

// ---------------------------------------------------------------------------
// weight f32 -> bf16 (RNE), concatenating [ih | hh] per row.  grid = rows.
// Proven in R5.  For single-matrix conversion pass Kb = 0 (bsrc unused).
// ---------------------------------------------------------------------------
__global__ __launch_bounds__(256) void k_cvt2(
    const float* __restrict__ a, const float* __restrict__ bsrc,
    unsigned short* __restrict__ dst, int Ka, int Kb)
{
    int r = blockIdx.x;
    int K = Ka + Kb;
    const float* ra = a + (size_t)r * Ka;
    const float* rb = bsrc + (size_t)r * Kb;
    unsigned short* d = dst + (size_t)r * K;
    for (int k4 = threadIdx.x * 4; k4 < K; k4 += 1024) {
        float4 v = (k4 < Ka) ? *(const float4*)(ra + k4)
                             : *(const float4*)(rb + (k4 - Ka));
        ushort4 u;
        u.x = f2bf(v.x); u.y = f2bf(v.y); u.z = f2bf(v.z); u.w = f2bf(v.w);
        *(ushort4*)(d + k4) = u;
    }
}

// ---------------------------------------------------------------------------
// pmem (bf16 out): pmem[r][k] = sum_j mem[r][j]*w_in[j][k]
// ---------------------------------------------------------------------------
__global__ __launch_bounds__(256) void k_pmem_bf(
    const float* __restrict__ mem, const float* __restrict__ w_in,
    unsigned short* __restrict__ pmem)
{
    __shared__ float As[64][36];
    __shared__ float Bs[32][68];

    const int tid = threadIdx.x;
    const int rt = blockIdx.x * 64;
    const int ct = blockIdx.y * 64;
    const int tx = tid & 15;
    const int ty = tid >> 4;

    float acc[4][4] = {{0.f}};

    for (int jc = 0; jc < 1024; jc += 32) {
        #pragma unroll
        for (int i = 0; i < 2; ++i) {
            int s2  = tid + i * 256;
            int row = s2 >> 3, kq = s2 & 7;
            *(float4*)&As[row][kq * 4] =
                *(const float4*)(mem + (size_t)(rt + row) * 1024 + jc + kq * 4);
        }
        #pragma unroll
        for (int i = 0; i < 2; ++i) {
            int s2 = tid + i * 256;
            int kk = s2 >> 4, cq = s2 & 15;
            *(float4*)&Bs[kk][cq * 4] =
                *(const float4*)(w_in + (size_t)(jc + kk) * 1024 + ct + cq * 4);
        }
        __syncthreads();

        #pragma unroll
        for (int kk = 0; kk < 32; ++kk) {
            float a0 = As[ty * 4 + 0][kk], a1 = As[ty * 4 + 1][kk];
            float a2 = As[ty * 4 + 2][kk], a3 = As[ty * 4 + 3][kk];
            float b0 = Bs[kk][tx * 4 + 0], b1 = Bs[kk][tx * 4 + 1];
            float b2 = Bs[kk][tx * 4 + 2], b3 = Bs[kk][tx * 4 + 3];
            acc[0][0] += a0 * b0; acc[0][1] += a0 * b1; acc[0][2] += a0 * b2; acc[0][3] += a0 * b3;
            acc[1][0] += a1 * b0; acc[1][1] += a1 * b1; acc[1][2] += a1 * b2; acc[1][3] += a1 * b3;
            acc[2][0] += a2 * b0; acc[2][1] += a2 * b1; acc[2][2] += a2 * b2; acc[2][3] += a2 * b3;
            acc[3][0] += a3 * b0; acc[3][1] += a3 * b1; acc[3][2] += a3 * b2; acc[3][3] += a3 * b3;
        }
        __syncthreads();
    }

    #pragma unroll
    for (int i = 0; i < 4; ++i) {
        ushort4 u;
        u.x = f2bf(acc[i][0]); u.y = f2bf(acc[i][1]);
        u.z = f2bf(acc[i][2]); u.w = f2bf(acc[i][3]);
        *(ushort4*)(pmem + (size_t)(rt + ty * 4 + i) * 1024 + ct + tx * 4) = u;
    }
}

// ---------------------------------------------------------------------------
// pmem f32 (fallback tier)
// ---------------------------------------------------------------------------
__global__ __launch_bounds__(256) void k_pmem(
    const float* __restrict__ mem, const float* __restrict__ w_in,
    float* __restrict__ pmem)
{
    __shared__ float As[64][36];
    __shared__ float Bs[32][68];

    const int tid = threadIdx.x;
    const int rt = blockIdx.x * 64;
    const int ct = blockIdx.y * 64;
    const int tx = tid & 15;
    const int ty = tid >> 4;

    float acc[4][4] = {{0.f}};

    for (int jc = 0; jc < 1024; jc += 32) {
        #pragma unroll
        for (int i = 0; i < 2; ++i) {
            int s2  = tid + i * 256;
            int row = s2 >> 3, kq = s2 & 7;
            *(float4*)&As[row][kq * 4] =
                *(const float4*)(mem + (size_t)(rt + row) * 1024 + jc + kq * 4);
        }
        #pragma unroll
        for (int i = 0; i < 2; ++i) {
            int s2 = tid + i * 256;
            int kk = s2 >> 4, cq = s2 & 15;
            *(float4*)&Bs[kk][cq * 4] =
                *(const float4*)(w_in + (size_t)(jc + kk) * 1024 + ct + cq * 4);
        }
        __syncthreads();

        #pragma unroll
        for (int kk = 0; kk < 32; ++kk) {
            float a0 = As[ty * 4 + 0][kk], a1 = As[ty * 4 + 1][kk];
            float a2 = As[ty * 4 + 2][kk], a3 = As[ty * 4 + 3][kk];
            float b0 = Bs[kk][tx * 4 + 0], b1 = Bs[kk][tx * 4 + 1];
            float b2 = Bs[kk][tx * 4 + 2], b3 = Bs[kk][tx * 4 + 3];
            acc[0][0] += a0 * b0; acc[0][1] += a0 * b1; acc[0][2] += a0 * b2; acc[0][3] += a0 * b3;
            acc[1][0] += a1 * b0; acc[1][1] += a1 * b1; acc[1][2] += a1 * b2; acc[1][3] += a1 * b3;
            acc[2][0] += a2 * b0; acc[2][1] += a2 * b1; acc[2][2] += a2 * b2; acc[2][3] += a2 * b3;
            acc[3][0] += a3 * b0; acc[3][1] += a3 * b1; acc[3][2] += a3 * b2; acc[3][3] += a3 * b3;
        }
        __syncthreads();
    }

    #pragma unroll
    for (int i = 0; i < 4; ++i) {
        float4 v = make_float4(acc[i][0], acc[i][1], acc[i][2], acc[i][3]);
        *(float4*)(pmem + (size_t)(rt + ty * 4 + i) * 1024 + ct + tx * 4) = v;
    }
}

// ===========================================================================
// bf16-weight GEMMs in the PROVEN round-2 skeleton: grid 512, block 256 =
// 32 b x 2 jl x 4 ks, f32 A staged in 38 KB LDS (no >64KB cliff), weights
// read as uint4 = 8 bf16/instr (half the instructions & bytes of f32).
// ===========================================================================

// -------- LSTM layer 0: K = 2560 = [emb 512 | feed 1024 | h0 1024] ---------
__global__ __launch_bounds__(256) void k_lstm0b(
    const int* __restrict__ tgt, const float* __restrict__ emb,
    const unsigned short* __restrict__ wb,
    const float* __restrict__ b_ih, const float* __restrict__ b_hh,
    const float* __restrict__ feed, const float* __restrict__ h0c,
    const float* __restrict__ c0c,
    float* __restrict__ h0n, float* __restrict__ c0n, int t)
{
    __shared__ float As[4][32][68];
    __shared__ float red[3][64][4];
    __shared__ int   tok[32];

    int tid = threadIdx.x;
    int b  = tid & 31;
    int jl = (tid >> 5) & 1;
    int ks = tid >> 6;
    int j  = blockIdx.x * 2 + jl;

    if (tid < 32) tok[tid] = tgt[tid * T_ + t];
    __syncthreads();

    float acc0, acc1, acc2, acc3;
    if (ks == 0) {
        acc0 = b_ih[0 * H_ + j] + b_hh[0 * H_ + j];
        acc1 = b_ih[1 * H_ + j] + b_hh[1 * H_ + j];
        acc2 = b_ih[2 * H_ + j] + b_hh[2 * H_ + j];
        acc3 = b_ih[3 * H_ + j] + b_hh[3 * H_ + j];
    } else {
        acc0 = acc1 = acc2 = acc3 = 0.0f;
    }

    const unsigned short* w0 = wb + (size_t)(0 * H_ + j) * 2560;
    const unsigned short* w1 = wb + (size_t)(1 * H_ + j) * 2560;
    const unsigned short* w2 = wb + (size_t)(2 * H_ + j) * 2560;
    const unsigned short* w3 = wb + (size_t)(3 * H_ + j) * 2560;

    for (int c = 0; c < 10; ++c) {
        #pragma unroll
        for (int i = 0; i < 8; ++i) {
            int q   = tid + i * 256;
            int ksq = q >> 9;
            int rem = q & 511;
            int bb  = rem >> 4;
            int kq  = rem & 15;
            int kg  = ksq * 640 + c * 64 + kq * 4;
            const float* src;
            if (kg < 512)        src = emb  + (size_t)tok[bb] * E_ + kg;
            else if (kg < 1536)  src = feed + (size_t)bb * H_ + (kg - 512);
            else                 src = h0c  + (size_t)bb * H_ + (kg - 1536);
            *(float4*)&As[ksq][bb][kq * 4] = *(const float4*)src;
        }
        __syncthreads();

        int kbase = ks * 640 + c * 64;
        const uint4* W0 = (const uint4*)(w0 + kbase);
        const uint4* W1 = (const uint4*)(w1 + kbase);
        const uint4* W2 = (const uint4*)(w2 + kbase);
        const uint4* W3 = (const uint4*)(w3 + kbase);
        const float4* A4 = (const float4*)&As[ks][b][0];
        #pragma unroll
        for (int kk = 0; kk < 8; ++kk) {
            float4 alo = A4[kk * 2];
            float4 ahi = A4[kk * 2 + 1];
            uint4 wv;
            wv = W0[kk];
            acc0 += alo.x*bflo(wv.x)+alo.y*bfhi(wv.x)+alo.z*bflo(wv.y)+alo.w*bfhi(wv.y)
                  + ahi.x*bflo(wv.z)+ahi.y*bfhi(wv.z)+ahi.z*bflo(wv.w)+ahi.w*bfhi(wv.w);
            wv = W1[kk];
            acc1 += alo.x*bflo(wv.x)+alo.y*bfhi(wv.x)+alo.z*bflo(wv.y)+alo.w*bfhi(wv.y)
                  + ahi.x*bflo(wv.z)+ahi.y*bfhi(wv.z)+ahi.z*bflo(wv.w)+ahi.w*bfhi(wv.w);
            wv = W2[kk];
            acc2 += alo.x*bflo(wv.x)+alo.y*bfhi(wv.x)+alo.z*bflo(wv.y)+alo.w*bfhi(wv.y)
                  + ahi.x*bflo(wv.z)+ahi.y*bfhi(wv.z)+ahi.z*bflo(wv.w)+ahi.w*bfhi(wv.w);
            wv = W3[kk];
            acc3 += alo.x*bflo(wv.x)+alo.y*bfhi(wv.x)+alo.z*bflo(wv.y)+alo.w*bfhi(wv.y)
                  + ahi.x*bflo(wv.z)+ahi.y*bfhi(wv.z)+ahi.z*bflo(wv.w)+ahi.w*bfhi(wv.w);
        }
        __syncthreads();
    }

    int idx = tid & 63;
    if (ks > 0) {
        red[ks - 1][idx][0] = acc0; red[ks - 1][idx][1] = acc1;
        red[ks - 1][idx][2] = acc2; red[ks - 1][idx][3] = acc3;
    }
    __syncthreads();
    if (ks == 0) {
        #pragma unroll
        for (int r = 0; r < 3; ++r) {
            acc0 += red[r][idx][0]; acc1 += red[r][idx][1];
            acc2 += red[r][idx][2]; acc3 += red[r][idx][3];
        }
        float co = c0c[b * H_ + j];
        float cn = sigm(acc1) * co + sigm(acc0) * tanh_(acc2);
        float hn = sigm(acc3) * tanh_(cn);
        c0n[b * H_ + j] = cn;
        h0n[b * H_ + j] = hn;
    }
}

// -------- LSTM layer 1: K = 2048 = [h0n 1024 | h1 1024] --------------------
__global__ __launch_bounds__(256) void k_lstm1b(
    const unsigned short* __restrict__ wb,
    const float* __restrict__ b_ih, const float* __restrict__ b_hh,
    const float* __restrict__ x, const float* __restrict__ h1c,
    const float* __restrict__ c1c,
    float* __restrict__ h1n, float* __restrict__ c1n)
{
    __shared__ float As[4][32][68];
    __shared__ float red[3][64][4];

    int tid = threadIdx.x;
    int b  = tid & 31;
    int jl = (tid >> 5) & 1;
    int ks = tid >> 6;
    int j  = blockIdx.x * 2 + jl;

    float acc0, acc1, acc2, acc3;
    if (ks == 0) {
        acc0 = b_ih[0 * H_ + j] + b_hh[0 * H_ + j];
        acc1 = b_ih[1 * H_ + j] + b_hh[1 * H_ + j];
        acc2 = b_ih[2 * H_ + j] + b_hh[2 * H_ + j];
        acc3 = b_ih[3 * H_ + j] + b_hh[3 * H_ + j];
    } else {
        acc0 = acc1 = acc2 = acc3 = 0.0f;
    }

    const unsigned short* w0 = wb + (size_t)(0 * H_ + j) * 2048;
    const unsigned short* w1 = wb + (size_t)(1 * H_ + j) * 2048;
    const unsigned short* w2 = wb + (size_t)(2 * H_ + j) * 2048;
    const unsigned short* w3 = wb + (size_t)(3 * H_ + j) * 2048;

    for (int c = 0; c < 8; ++c) {
        #pragma unroll
        for (int i = 0; i < 8; ++i) {
            int q   = tid + i * 256;
            int ksq = q >> 9;
            int rem = q & 511;
            int bb  = rem >> 4;
            int kq  = rem & 15;
            int kg  = ksq * 512 + c * 64 + kq * 4;
            const float* src = (kg < 1024) ? (x + (size_t)bb * H_ + kg)
                                           : (h1c + (size_t)bb * H_ + (kg - 1024));
            *(float4*)&As[ksq][bb][kq * 4] = *(const float4*)src;
        }
        __syncthreads();

        int kbase = ks * 512 + c * 64;
        const uint4* W0 = (const uint4*)(w0 + kbase);
        const uint4* W1 = (const uint4*)(w1 + kbase);
        const uint4* W2 = (const uint4*)(w2 + kbase);
        const uint4* W3 = (const uint4*)(w3 + kbase);
        const float4* A4 = (const float4*)&As[ks][b][0];
        #pragma unroll
        for (int kk = 0; kk < 8; ++kk) {
            float4 alo = A4[kk * 2];
            float4 ahi = A4[kk * 2 + 1];
            uint4 wv;
            wv = W0[kk];
            acc0 += alo.x*bflo(wv.x)+alo.y*bfhi(wv.x)+alo.z*bflo(wv.y)+alo.w*bfhi(wv.y)
                  + ahi.x*bflo(wv.z)+ahi.y*bfhi(wv.z)+ahi.z*bflo(wv.w)+ahi.w*bfhi(wv.w);
            wv = W1[kk];
            acc1 += alo.x*bflo(wv.x)+alo.y*bfhi(wv.x)+alo.z*bflo(wv.y)+alo.w*bfhi(wv.y)
                  + ahi.x*bflo(wv.z)+ahi.y*bfhi(wv.z)+ahi.z*bflo(wv.w)+ahi.w*bfhi(wv.w);
            wv = W2[kk];
            acc2 += alo.x*bflo(wv.x)+alo.y*bfhi(wv.x)+alo.z*bflo(wv.y)+alo.w*bfhi(wv.y)
                  + ahi.x*bflo(wv.z)+ahi.y*bfhi(wv.z)+ahi.z*bflo(wv.w)+ahi.w*bfhi(wv.w);
            wv = W3[kk];
            acc3 += alo.x*bflo(wv.x)+alo.y*bfhi(wv.x)+alo.z*bflo(wv.y)+alo.w*bfhi(wv.y)
                  + ahi.x*bflo(wv.z)+ahi.y*bfhi(wv.z)+ahi.z*bflo(wv.w)+ahi.w*bfhi(wv.w);
        }
        __syncthreads();
    }

    int idx = tid & 63;
    if (ks > 0) {
        red[ks - 1][idx][0] = acc0; red[ks - 1][idx][1] = acc1;
        red[ks - 1][idx][2] = acc2; red[ks - 1][idx][3] = acc3;
    }
    __syncthreads();
    if (ks == 0) {
        #pragma unroll
        for (int r = 0; r < 3; ++r) {
            acc0 += red[r][idx][0]; acc1 += red[r][idx][1];
            acc2 += red[r][idx][2]; acc3 += red[r][idx][3];
        }
        float co = c1c[b * H_ + j];
        float cn = sigm(acc1) * co + sigm(acc0) * tanh_(acc2);
        float hn = sigm(acc3) * tanh_(cn);
        c1n[b * H_ + j] = cn;
        h1n[b * H_ + j] = hn;
    }
}

// -------- out = tanh([ctx | h1n] @ w_out^T), bf16 weights ------------------
__global__ __launch_bounds__(256) void k_outb(
    const unsigned short* __restrict__ wo, const float* __restrict__ ctx,
    const float* __restrict__ h1n,
    float* __restrict__ feedn, float* __restrict__ dout, int t)
{
    __shared__ float As[4][32][68];
    __shared__ float red[3][64];

    int tid = threadIdx.x;
    int b  = tid & 31;
    int jl = (tid >> 5) & 1;
    int ks = tid >> 6;
    int j  = blockIdx.x * 2 + jl;

    float acc = 0.0f;
    const unsigned short* w0 = wo + (size_t)j * 2048;

    for (int c = 0; c < 8; ++c) {
        #pragma unroll
        for (int i = 0; i < 8; ++i) {
            int q   = tid + i * 256;
            int ksq = q >> 9;
            int rem = q & 511;
            int bb  = rem >> 4;
            int kq  = rem & 15;
            int kg  = ksq * 512 + c * 64 + kq * 4;
            const float* src = (kg < 1024) ? (ctx + (size_t)bb * H_ + kg)
                                           : (h1n + (size_t)bb * H_ + (kg - 1024));
            *(float4*)&As[ksq][bb][kq * 4] = *(const float4*)src;
        }
        __syncthreads();

        int kbase = ks * 512 + c * 64;
        const uint4* W0 = (const uint4*)(w0 + kbase);
        const float4* A4 = (const float4*)&As[ks][b][0];
        #pragma unroll
        for (int kk = 0; kk < 8; ++kk) {
            float4 alo = A4[kk * 2];
            float4 ahi = A4[kk * 2 + 1];
            uint4 wv = W0[kk];
            acc += alo.x*bflo(wv.x)+alo.y*bfhi(wv.x)+alo.z*bflo(wv.y)+alo.w*bfhi(wv.y)
                 + ahi.x*bflo(wv.z)+ahi.y*bfhi(wv.z)+ahi.z*bflo(wv.w)+ahi.w*bfhi(wv.w);
        }
        __syncthreads();
    }

    int idx = tid & 63;
    if (ks > 0) red[ks - 1][idx] = acc;
    __syncthreads();
    if (ks == 0) {
        acc += red[0][idx] + red[1][idx] + red[2][idx];
        float o = tanh_(acc);
        feedn[b * H_ + j] = o;
        dout[((size_t)b * T_ + t) * H_ + j] = o;
    }
}

// ---------------------------------------------------------------------------
// scores vs bf16 pmem: scores[b][s] = h1[b] . pmem[b][s]
// ---------------------------------------------------------------------------
__global__ __launch_bounds__(256) void k_scores_bf(
    const float* __restrict__ x_in, const unsigned short* __restrict__ base,
    float* __restrict__ sc_out)
{
    __shared__ float q_lds[1024];

    int b  = blockIdx.x >> 4;
    int st = blockIdx.x & 15;
    int tid  = threadIdx.x;
    int lane = tid & 63;
    int wv   = tid >> 6;

    ((float4*)q_lds)[tid] = ((const float4*)(x_in + (size_t)b * H_))[tid];
    __syncthreads();

    float4 qa[2][2];
    #pragma unroll
    for (int i = 0; i < 2; ++i) {
        int u = lane + 64 * i;
        qa[i][0] = ((const float4*)q_lds)[2 * u];
        qa[i][1] = ((const float4*)q_lds)[2 * u + 1];
    }

    const unsigned short* mb = base + (size_t)b * S_ * H_;
    #pragma unroll
    for (int ss = 0; ss < 4; ++ss) {
        int s = st * 16 + wv * 4 + ss;
        const uint4* mr = (const uint4*)(mb + (size_t)s * H_);
        float a = 0.0f;
        #pragma unroll
        for (int i = 0; i < 2; ++i) {
            uint4 m = mr[lane + 64 * i];
            float4 lo = qa[i][0], hi = qa[i][1];
            a += lo.x*bflo(m.x)+lo.y*bfhi(m.x)+lo.z*bflo(m.y)+lo.w*bfhi(m.y)
               + hi.x*bflo(m.z)+hi.y*bfhi(m.z)+hi.z*bflo(m.w)+hi.w*bfhi(m.w);
        }
        #pragma unroll
        for (int o = 32; o > 0; o >>= 1) a += __shfl_down(a, o);
        if (lane == 0) sc_out[b * S_ + s] = a;
    }
}

// ---------------------------------------------------------------------------
// ctx: local masked softmax of scores + weighted sum (f32 mem, unchanged)
// ---------------------------------------------------------------------------
__global__ __launch_bounds__(256) void k_ctx(
    const float* __restrict__ sc_in, const float* __restrict__ mem,
    const int* __restrict__ masks,
    float* __restrict__ ctx, float* __restrict__ attn_out, int t)
{
    __shared__ float aw[256];
    __shared__ float red2[4][64];

    int b  = blockIdx.x >> 4;
    int ht = blockIdx.x & 15;
    int tid  = threadIdx.x;
    int lane = tid & 63;
    int wv   = tid >> 6;

    if (wv == 0) {
        int m = 0;
        #pragma unroll
        for (int i = 0; i < 4; ++i) m += masks[b * S_ + lane * 4 + i];
        #pragma unroll
        for (int o = 32; o > 0; o >>= 1) m += __shfl_down(m, o);
        int len = __shfl(m, 0);

        float v[4];
        float mx = -1e30f;
        #pragma unroll
        for (int i = 0; i < 4; ++i) {
            int s = lane + 64 * i;
            float xv = (s < len) ? sc_in[b * S_ + s] : -1e9f;
            v[i] = xv;
            mx = fmaxf(mx, xv);
        }
        #pragma unroll
        for (int o = 32; o > 0; o >>= 1) mx = fmaxf(mx, __shfl_xor(mx, o));
        float sm = 0.0f;
        #pragma unroll
        for (int i = 0; i < 4; ++i) { v[i] = __expf(v[i] - mx); sm += v[i]; }
        #pragma unroll
        for (int o = 32; o > 0; o >>= 1) sm += __shfl_xor(sm, o);
        float inv = 1.0f / sm;
        #pragma unroll
        for (int i = 0; i < 4; ++i) {
            int s = lane + 64 * i;
            float w = v[i] * inv;
            aw[s] = w;
            if (ht == 0) attn_out[((size_t)b * T_ + t) * S_ + s] = w;
        }
    }
    __syncthreads();

    int h = ht * 64 + lane;
    const float* mb = mem + (size_t)b * S_ * H_;
    float a = 0.0f;
    #pragma unroll 8
    for (int ss = 0; ss < 64; ++ss) {
        int s = wv * 64 + ss;
        a += aw[s] * mb[(size_t)s * H_ + h];
    }
    red2[wv][lane] = a;
    __syncthreads();
    if (tid < 64) {
        float r = red2[0][tid] + red2[1][tid] + red2[2][tid] + red2[3][tid];
        ctx[b * H_ + ht * 64 + tid] = r;
    }
}

// ===========================================================================
// f32 fallback kernels (R7 champion path, proven 8.03 ms)
// ===========================================================================
__global__ __launch_bounds__(256) void k_lstm0(
    const int* __restrict__ tgt, const float* __restrict__ emb,
    const float* __restrict__ w_ih0, const float* __restrict__ w_hh0,
    const float* __restrict__ b_ih0, const float* __restrict__ b_hh0,
    const float* __restrict__ feed, const float* __restrict__ h0c,
    const float* __restrict__ c0c,
    float* __restrict__ h0n, float* __restrict__ c0n, int t)
{
    __shared__ float As[4][32][68];
    __shared__ float red[3][64][4];
    __shared__ int   tok[32];

    int tid = threadIdx.x;
    int b  = tid & 31;
    int jl = (tid >> 5) & 1;
    int ks = tid >> 6;
    int j  = blockIdx.x * 2 + jl;

    if (tid < 32) tok[tid] = tgt[tid * T_ + t];
    __syncthreads();

    float acc0, acc1, acc2, acc3;
    if (ks == 0) {
        acc0 = b_ih0[0 * H_ + j] + b_hh0[0 * H_ + j];
        acc1 = b_ih0[1 * H_ + j] + b_hh0[1 * H_ + j];
        acc2 = b_ih0[2 * H_ + j] + b_hh0[2 * H_ + j];
        acc3 = b_ih0[3 * H_ + j] + b_hh0[3 * H_ + j];
    } else {
        acc0 = acc1 = acc2 = acc3 = 0.0f;
    }

    for (int c = 0; c < 10; ++c) {
        #pragma unroll
        for (int i = 0; i < 8; ++i) {
            int q   = tid + i * 256;
            int ksq = q >> 9;
            int rem = q & 511;
            int bb  = rem >> 4;
            int kq  = rem & 15;
            int kg  = ksq * 640 + c * 64 + kq * 4;
            const float* src;
            if (kg < 512)        src = emb  + (size_t)tok[bb] * E_ + kg;
            else if (kg < 1536)  src = feed + (size_t)bb * H_ + (kg - 512);
            else                 src = h0c  + (size_t)bb * H_ + (kg - 1536);
            *(float4*)&As[ksq][bb][kq * 4] = *(const float4*)src;
        }
        __syncthreads();

        int kbase = ks * 640 + c * 64;
        const float4 *w0, *w1, *w2, *w3;
        if (kbase < 1536) {
            w0 = (const float4*)(w_ih0 + (size_t)(0 * H_ + j) * 1536 + kbase);
            w1 = (const float4*)(w_ih0 + (size_t)(1 * H_ + j) * 1536 + kbase);
            w2 = (const float4*)(w_ih0 + (size_t)(2 * H_ + j) * 1536 + kbase);
            w3 = (const float4*)(w_ih0 + (size_t)(3 * H_ + j) * 1536 + kbase);
        } else {
            int kb = kbase - 1536;
            w0 = (const float4*)(w_hh0 + (size_t)(0 * H_ + j) * 1024 + kb);
            w1 = (const float4*)(w_hh0 + (size_t)(1 * H_ + j) * 1024 + kb);
            w2 = (const float4*)(w_hh0 + (size_t)(2 * H_ + j) * 1024 + kb);
            w3 = (const float4*)(w_hh0 + (size_t)(3 * H_ + j) * 1024 + kb);
        }
        const float4* A4 = (const float4*)&As[ks][b][0];
        #pragma unroll
        for (int kk = 0; kk < 16; ++kk) {
            float4 a  = A4[kk];
            float4 q0 = w0[kk], q1 = w1[kk], q2 = w2[kk], q3 = w3[kk];
            acc0 += a.x * q0.x + a.y * q0.y + a.z * q0.z + a.w * q0.w;
            acc1 += a.x * q1.x + a.y * q1.y + a.z * q1.z + a.w * q1.w;
            acc2 += a.x * q2.x + a.y * q2.y + a.z * q2.z + a.w * q2.w;
            acc3 += a.x * q3.x + a.y * q3.y + a.z * q3.z + a.w * q3.w;
        }
        __syncthreads();
    }

    int idx = tid & 63;
    if (ks > 0) {
        red[ks - 1][idx][0] = acc0; red[ks - 1][idx][1] = acc1;
        red[ks - 1][idx][2] = acc2; red[ks - 1][idx][3] = acc3;
    }
    __syncthreads();
    if (ks == 0) {
        #pragma unroll
        for (int r = 0; r < 3; ++r) {
            acc0 += red[r][idx][0]; acc1 += red[r][idx][1];
            acc2 += red[r][idx][2]; acc3 += red[r][idx][3];
        }
        float co = c0c[b * H_ + j];
        float cn = sigm(acc1) * co + sigm(acc0) * tanh_(acc2);
        float hn = sigm(acc3) * tanh_(cn);
        c0n[b * H_ + j] = cn;
        h0n[b * H_ + j] = hn;
    }
}

__global__ __launch_bounds__(256) void k_lstm1(
    const float* __restrict__ w_ih1, const float* __restrict__ w_hh1,
    const float* __restrict__ b_ih1, const float* __restrict__ b_hh1,
    const float* __restrict__ x, const float* __restrict__ h1c,
    const float* __restrict__ c1c,
    float* __restrict__ h1n, float* __restrict__ c1n)
{
    __shared__ float As[4][32][68];
    __shared__ float red[3][64][4];

    int tid = threadIdx.x;
    int b  = tid & 31;
    int jl = (tid >> 5) & 1;
    int ks = tid >> 6;
    int j  = blockIdx.x * 2 + jl;

    float acc0, acc1, acc2, acc3;
    if (ks == 0) {
        acc0 = b_ih1[0 * H_ + j] + b_hh1[0 * H_ + j];
        acc1 = b_ih1[1 * H_ + j] + b_hh1[1 * H_ + j];
        acc2 = b_ih1[2 * H_ + j] + b_hh1[2 * H_ + j];
        acc3 = b_ih1[3 * H_ + j] + b_hh1[3 * H_ + j];
    } else {
        acc0 = acc1 = acc2 = acc3 = 0.0f;
    }

    for (int c = 0; c < 8; ++c) {
        #pragma unroll
        for (int i = 0; i < 8; ++i) {
            int q   = tid + i * 256;
            int ksq = q >> 9;
            int rem = q & 511;
            int bb  = rem >> 4;
            int kq  = rem & 15;
            int kg  = ksq * 512 + c * 64 + kq * 4;
            const float* src = (kg < 1024) ? (x + (size_t)bb * H_ + kg)
                                           : (h1c + (size_t)bb * H_ + (kg - 1024));
            *(float4*)&As[ksq][bb][kq * 4] = *(const float4*)src;
        }
        __syncthreads();

        int kbase = ks * 512 + c * 64;
        const float* wb;
        int ko;
        if (kbase < 1024) { wb = w_ih1; ko = kbase; }
        else              { wb = w_hh1; ko = kbase - 1024; }
        const float4* w0 = (const float4*)(wb + (size_t)(0 * H_ + j) * H_ + ko);
        const float4* w1 = (const float4*)(wb + (size_t)(1 * H_ + j) * H_ + ko);
        const float4* w2 = (const float4*)(wb + (size_t)(2 * H_ + j) * H_ + ko);
        const float4* w3 = (const float4*)(wb + (size_t)(3 * H_ + j) * H_ + ko);
        const float4* A4 = (const float4*)&As[ks][b][0];
        #pragma unroll
        for (int kk = 0; kk < 16; ++kk) {
            float4 a  = A4[kk];
            float4 q0 = w0[kk], q1 = w1[kk], q2 = w2[kk], q3 = w3[kk];
            acc0 += a.x * q0.x + a.y * q0.y + a.z * q0.z + a.w * q0.w;
            acc1 += a.x * q1.x + a.y * q1.y + a.z * q1.z + a.w * q1.w;
            acc2 += a.x * q2.x + a.y * q2.y + a.z * q2.z + a.w * q2.w;
            acc3 += a.x * q3.x + a.y * q3.y + a.z * q3.z + a.w * q3.w;
        }
        __syncthreads();
    }

    int idx = tid & 63;
    if (ks > 0) {
        red[ks - 1][idx][0] = acc0; red[ks - 1][idx][1] = acc1;
        red[ks - 1][idx][2] = acc2; red[ks - 1][idx][3] = acc3;
    }
    __syncthreads();
    if (ks == 0) {
        #pragma unroll
        for (int r = 0; r < 3; ++r) {
            acc0 += red[r][idx][0]; acc1 += red[r][idx][1];
            acc2 += red[r][idx][2]; acc3 += red[r][idx][3];
        }
        float co = c1c[b * H_ + j];
        float cn = sigm(acc1) * co + sigm(acc0) * tanh_(acc2);
        float hn = sigm(acc3) * tanh_(cn);
        c1n[b * H_ + j] = cn;
        h1n[b * H_ + j] = hn;
    }
}

__global__ __launch_bounds__(256) void k_q(
    const float* __restrict__ w_in, const float* __restrict__ h1n,
    float* __restrict__ q_out)
{
    __shared__ float As[4][32][68];
    __shared__ float red[3][64];

    int tid = threadIdx.x;
    int b  = tid & 31;
    int jl = (tid >> 5) & 1;
    int ks = tid >> 6;
    int j  = blockIdx.x * 2 + jl;

    float acc = 0.0f;
    for (int c = 0; c < 4; ++c) {
        #pragma unroll
        for (int i = 0; i < 8; ++i) {
            int q   = tid + i * 256;
            int ksq = q >> 9;
            int rem = q & 511;
            int bb  = rem >> 4;
            int kq  = rem & 15;
            int kg  = ksq * 256 + c * 64 + kq * 4;
            *(float4*)&As[ksq][bb][kq * 4] = *(const float4*)(h1n + (size_t)bb * H_ + kg);
        }
        __syncthreads();

        int kbase = ks * 256 + c * 64;
        const float4* w0 = (const float4*)(w_in + (size_t)j * H_ + kbase);
        const float4* A4 = (const float4*)&As[ks][b][0];
        #pragma unroll
        for (int kk = 0; kk < 16; ++kk) {
            float4 a  = A4[kk];
            float4 q0 = w0[kk];
            acc += a.x * q0.x + a.y * q0.y + a.z * q0.z + a.w * q0.w;
        }
        __syncthreads();
    }

    int idx = tid & 63;
    if (ks > 0) red[ks - 1][idx] = acc;
    __syncthreads();
    if (ks == 0) {
        acc += red[0][idx] + red[1][idx] + red[2][idx];
        q_out[b * H_ + j] = acc;
    }
}

__global__ __launch_bounds__(256) void k_scores(
    const float* __restrict__ x_in, const float* __restrict__ base,
    float* __restrict__ sc_out)
{
    __shared__ float q_lds[1024];

    int b  = blockIdx.x >> 4;
    int st = blockIdx.x & 15;
    int tid  = threadIdx.x;
    int lane = tid & 63;
    int wv   = tid >> 6;

    ((float4*)q_lds)[tid] = ((const float4*)(x_in + (size_t)b * H_))[tid];
    __syncthreads();

    float4 q4[4];
    #pragma unroll
    for (int i = 0; i < 4; ++i) q4[i] = ((const float4*)q_lds)[lane + 64 * i];

    const float* mb = base + (size_t)b * S_ * H_;
    #pragma unroll
    for (int ss = 0; ss < 4; ++ss) {
        int s = st * 16 + wv * 4 + ss;
        const float4* mr = (const float4*)(mb + (size_t)s * H_);
        float a = 0.0f;
        #pragma unroll
        for (int i = 0; i < 4; ++i) {
            float4 m = mr[lane + 64 * i];
            a += q4[i].x * m.x + q4[i].y * m.y + q4[i].z * m.z + q4[i].w * m.w;
        }
        #pragma unroll
        for (int o = 32; o > 0; o >>= 1) a += __shfl_down(a, o);
        if (lane == 0) sc_out[b * S_ + s] = a;
    }
}

__global__ __launch_bounds__(256) void k_out(
    const float* __restrict__ w_out, const float* __restrict__ ctx,
    const float* __restrict__ h1n,
    float* __restrict__ feedn, float* __restrict__ dout, int t)
{
    __shared__ float As[4][32][68];
    __shared__ float red[3][64];

    int tid = threadIdx.x;
    int b  = tid & 31;
    int jl = (tid >> 5) & 1;
    int ks = tid >> 6;
    int j  = blockIdx.x * 2 + jl;

    float acc = 0.0f;
    for (int c = 0; c < 8; ++c) {
        #pragma unroll
        for (int i = 0; i < 8; ++i) {
            int q   = tid + i * 256;
            int ksq = q >> 9;
            int rem = q & 511;
            int bb  = rem >> 4;
            int kq  = rem & 15;
            int kg  = ksq * 512 + c * 64 + kq * 4;
            const float* src = (kg < 1024) ? (ctx + (size_t)bb * H_ + kg)
                                           : (h1n + (size_t)bb * H_ + (kg - 1024));
            *(float4*)&As[ksq][bb][kq * 4] = *(const float4*)src;
        }
        __syncthreads();

        int kbase = ks * 512 + c * 64;
        const float4* w0 = (const float4*)(w_out + (size_t)j * 2048 + kbase);
        const float4* A4 = (const float4*)&As[ks][b][0];
        #pragma unroll
        for (int kk = 0; kk < 16; ++kk) {
            float4 a  = A4[kk];
            float4 q0 = w0[kk];
            acc += a.x * q0.x + a.y * q0.y + a.z * q0.z + a.w * q0.w;
        }
        __syncthreads();
    }

    int idx = tid & 63;
    if (ks > 0) red[ks - 1][idx] = acc;
    __syncthreads();
    if (ks == 0) {
        acc += red[0][idx] + red[1][idx] + red[2][idx];
        float o = tanh_(acc);
        feedn[b * H_ + j] = o;
        dout[((size_t)b * T_ + t) * H_ + j] = o;
    }
}

// ---------------------------------------------------------------------------
extern "C" void kernel_launch(void* const* d_in, const int* in_sizes, int n_in,
                              void* d_out, int out_size, void* d_ws, size_t ws_size,
                              hipStream_t stream) {
    const int*   tgt    = (const int*)  d_in[0];
    const float* mem    = (const float*)d_in[1];
    const int*   masks  = (const int*)  d_in[2];
    const float* h0in   = (const float*)d_in[3];
    const float* c0in   = (const float*)d_in[4];
    const float* emb    = (const float*)d_in[5];
    const float* w_ih0  = (const float*)d_in[6];
    const float* w_hh0  = (const float*)d_in[7];
    const float* b_ih0  = (const float*)d_in[8];
    const float* b_hh0  = (const float*)d_in[9];
    const float* w_ih1  = (const float*)d_in[10];
    const float* w_hh1  = (const float*)d_in[11];
    const float* b_ih1  = (const float*)d_in[12];
    const float* b_hh1  = (const float*)d_in[13];
    const float* w_in   = (const float*)d_in[14];
    const float* w_out  = (const float*)d_in[15];

    float* dout     = (float*)d_out;
    float* attn_out = dout + (size_t)B_ * T_ * H_;

    const size_t nwb0 = (size_t)4096 * 2560;      // shorts
    const size_t nwb1 = (size_t)4096 * 2048;
    const size_t nwo  = (size_t)1024 * 2048;
    const size_t npmb = (size_t)B_ * S_ * H_;     // shorts
    const size_t nfl  = (size_t)11 * BH_ + B_ * S_;
    const size_t needA = (nwb0 + nwb1 + nwo + npmb) * 2 + nfl * 4;
    const size_t needB = (nfl + (size_t)B_ * S_ * H_) * 4;

    if (ws_size >= needA) {
        // ---------- bf16 tier ----------
        unsigned short* wb0 = (unsigned short*)d_ws;
        unsigned short* wb1 = wb0 + nwb0;
        unsigned short* wo  = wb1 + nwb1;
        unsigned short* pmb = wo + nwo;
        float* fs   = (float*)(pmb + npmb);
        float* h0s  = fs;
        float* c0s  = h0s + 2 * BH_;
        float* h1s  = c0s + 2 * BH_;
        float* c1s  = h1s + 2 * BH_;
        float* feed = c1s + 2 * BH_;
        float* qctx = feed + 2 * BH_;
        float* scw  = qctx + BH_;

        k_cvt2<<<4096, 256, 0, stream>>>(w_ih0, w_hh0, wb0, 1536, 1024);
        k_cvt2<<<4096, 256, 0, stream>>>(w_ih1, w_hh1, wb1, 1024, 1024);
        k_cvt2<<<1024, 256, 0, stream>>>(w_out, w_out, wo, 2048, 0);
        k_init<<<128, 256, 0, stream>>>(h0in, c0in, h0s, c0s, h1s, c1s, feed);
        k_pmem_bf<<<dim3(128, 16), 256, 0, stream>>>(mem, w_in, pmb);

        for (int t = 0; t < T_; ++t) {
            int cur = t & 1, nxt = cur ^ 1;
            k_lstm0b<<<512, 256, 0, stream>>>(tgt, emb, wb0, b_ih0, b_hh0,
                                              feed + cur * BH_, h0s + cur * BH_, c0s + cur * BH_,
                                              h0s + nxt * BH_, c0s + nxt * BH_, t);
            k_lstm1b<<<512, 256, 0, stream>>>(wb1, b_ih1, b_hh1,
                                              h0s + nxt * BH_, h1s + cur * BH_, c1s + cur * BH_,
                                              h1s + nxt * BH_, c1s + nxt * BH_);
            k_scores_bf<<<512, 256, 0, stream>>>(h1s + nxt * BH_, pmb, scw);
            k_ctx<<<512, 256, 0, stream>>>(scw, mem, masks, qctx, attn_out, t);
            k_outb<<<512, 256, 0, stream>>>(wo, qctx, h1s + nxt * BH_,
                                            feed + nxt * BH_, dout, t);
        }
    } else if (ws_size >= needB) {
        // ---------- f32 + pmem tier (R7 champion) ----------
        float* ws   = (float*)d_ws;
        float* h0s  = ws;
        float* c0s  = h0s  + 2 * BH_;
        float* h1s  = c0s  + 2 * BH_;
        float* c1s  = h1s  + 2 * BH_;
        float* feed = c1s  + 2 * BH_;
        float* qctx = feed + 2 * BH_;
        float* scw  = qctx + BH_;
        float* pmem = scw  + B_ * S_;

        k_init<<<128, 256, 0, stream>>>(h0in, c0in, h0s, c0s, h1s, c1s, feed);
        k_pmem<<<dim3(128, 16), 256, 0, stream>>>(mem, w_in, pmem);

        for (int t = 0; t < T_; ++t) {
            int cur = t & 1, nxt = cur ^ 1;
            k_lstm0<<<512, 256, 0, stream>>>(tgt, emb, w_ih0, w_hh0, b_ih0, b_hh0,
                                             feed + cur * BH_, h0s + cur * BH_, c0s + cur * BH_,
                                             h0s + nxt * BH_, c0s + nxt * BH_, t);
            k_lstm1<<<512, 256, 0, stream>>>(w_ih1, w_hh1, b_ih1, b_hh1,
                                             h0s + nxt * BH_, h1s + cur * BH_, c1s + cur * BH_,
                                             h1s + nxt * BH_, c1s + nxt * BH_);
            k_scores<<<512, 256, 0, stream>>>(h1s + nxt * BH_, pmem, scw);
            k_ctx<<<512, 256, 0, stream>>>(scw, mem, masks, qctx, attn_out, t);
            k_out<<<512, 256, 0, stream>>>(w_out, qctx, h1s + nxt * BH_,
                                           feed + nxt * BH_, dout, t);
        }
    } else {
        // ---------- minimal tier (round-2) ----------
        float* ws   = (float*)d_ws;
        float* h0s  = ws;
        float* c0s  = h0s  + 2 * BH_;
        float* h1s  = c0s  + 2 * BH_;
        float* c1s  = h1s  + 2 * BH_;
        float* feed = c1s  + 2 * BH_;
        float* qctx = feed + 2 * BH_;
        float* scw  = qctx + BH_;

        k_init<<<128, 256, 0, stream>>>(h0in, c0in, h0s, c0s, h1s, c1s, feed);
        for (int t = 0; t < T_; ++t) {
            int cur = t & 1, nxt = cur ^ 1;
            k_lstm0<<<512, 256, 0, stream>>>(tgt, emb, w_ih0, w_hh0, b_ih0, b_hh0,
                                             feed + cur * BH_, h0s + cur * BH_, c0s + cur * BH_,
                                             h0s + nxt * BH_, c0s + nxt * BH_, t);
            k_lstm1<<<512, 256, 0, stream>>>(w_ih1, w_hh1, b_ih1, b_hh1,
                                             h0s + nxt * BH_, h1s + cur * BH_, c1s + cur * BH_,
                                             h1s + nxt * BH_, c1s + nxt * BH_);
            k_q<<<512, 256, 0, stream>>>(w_in, h1s + nxt * BH_, qctx);
            k_scores<<<512, 256, 0, stream>>>(qctx, mem, scw);
            k_ctx<<<512, 256, 0, stream>>>(scw, mem, masks, qctx, attn_out, t);
            k_out<<<512, 256, 0, stream>>>(w_out, qctx, h1s + nxt * BH_,
                                           feed + nxt * BH_, dout, t);
        }
    }
}

// Round 13
// 7694.529 us; speedup vs baseline: 1.1465x; 1.1465x over previous
//
#include <hip/hip_runtime.h>
#include <math.h>

#define B_ 32
#define T_ 64
#define S_ 256
#define H_ 1024
#define E_ 512
#define BH_ (B_ * H_)

__device__ __forceinline__ float sigm(float x) {
    return 1.0f / (1.0f + __expf(-x));
}
__device__ __forceinline__ float tanh_(float x) {
    x = fminf(15.0f, fmaxf(-15.0f, x));
    float e = __expf(-2.0f * x);
    return (1.0f - e) / (1.0f + e);
}

// ---------------------------------------------------------------------------
// init: state ping-pong slot 0 + zero input feed
// ---------------------------------------------------------------------------
__global__ void k_init(const float* __restrict__ h0in, const float* __restrict__ c0in,
                       float* h0s, float* c0s, float* h1s, float* c1s, float* feed) {
    int i = blockIdx.x * 256 + threadIdx.x;
    if (i < BH_) {
        h0s[i]  = h0in[i];
        h1s[i]  = h0in[BH_ + i];
        c0s[i]  = c0in[i];
        c1s[i]  = c0in[BH_ + i];
        feed[i] = 0.0f;
    }
}

// ---------------------------------------------------------------------------
// pmem[r][k] = sum_j mem[r][j] * w_in[j][k]   (time-invariant; R7-proven)
// grid (128, 16), block 256.  64x64 tile, K-chunk 32, 4x4 outputs/thread.
// ---------------------------------------------------------------------------
__global__ __launch_bounds__(256) void k_pmem(
    const float* __restrict__ mem, const float* __restrict__ w_in,
    float* __restrict__ pmem)
{
    __shared__ float As[64][36];   // [row][k]  +pad
    __shared__ float Bs[32][68];   // [k][col]  +pad

    const int tid = threadIdx.x;
    const int rt = blockIdx.x * 64;
    const int ct = blockIdx.y * 64;
    const int tx = tid & 15;
    const int ty = tid >> 4;

    float acc[4][4] = {{0.f}};

    for (int jc = 0; jc < 1024; jc += 32) {
        #pragma unroll
        for (int i = 0; i < 2; ++i) {
            int s2  = tid + i * 256;
            int row = s2 >> 3, kq = s2 & 7;
            *(float4*)&As[row][kq * 4] =
                *(const float4*)(mem + (size_t)(rt + row) * 1024 + jc + kq * 4);
        }
        #pragma unroll
        for (int i = 0; i < 2; ++i) {
            int s2 = tid + i * 256;
            int kk = s2 >> 4, cq = s2 & 15;
            *(float4*)&Bs[kk][cq * 4] =
                *(const float4*)(w_in + (size_t)(jc + kk) * 1024 + ct + cq * 4);
        }
        __syncthreads();

        #pragma unroll
        for (int kk = 0; kk < 32; ++kk) {
            float a0 = As[ty * 4 + 0][kk], a1 = As[ty * 4 + 1][kk];
            float a2 = As[ty * 4 + 2][kk], a3 = As[ty * 4 + 3][kk];
            float b0 = Bs[kk][tx * 4 + 0], b1 = Bs[kk][tx * 4 + 1];
            float b2 = Bs[kk][tx * 4 + 2], b3 = Bs[kk][tx * 4 + 3];
            acc[0][0] += a0 * b0; acc[0][1] += a0 * b1; acc[0][2] += a0 * b2; acc[0][3] += a0 * b3;
            acc[1][0] += a1 * b0; acc[1][1] += a1 * b1; acc[1][2] += a1 * b2; acc[1][3] += a1 * b3;
            acc[2][0] += a2 * b0; acc[2][1] += a2 * b1; acc[2][2] += a2 * b2; acc[2][3] += a2 * b3;
            acc[3][0] += a3 * b0; acc[3][1] += a3 * b1; acc[3][2] += a3 * b2; acc[3][3] += a3 * b3;
        }
        __syncthreads();
    }

    #pragma unroll
    for (int i = 0; i < 4; ++i) {
        float4 v = make_float4(acc[i][0], acc[i][1], acc[i][2], acc[i][3]);
        *(float4*)(pmem + (size_t)(rt + ty * 4 + i) * 1024 + ct + tx * 4) = v;
    }
}

// ---------------------------------------------------------------------------
// gemb[r][n] = sum_k emb[tgt[r]][k] * w_ih0[n][k]   (r = b*64+t; K = 512)
// grid (32, 64), block 256.  64x64 tile, K-chunk 32, 4x4 outputs/thread.
// B-tile loaded transposed-coalesced (along k within each w_ih0 row).
// ---------------------------------------------------------------------------
__global__ __launch_bounds__(256) void k_gemb(
    const int* __restrict__ tgt, const float* __restrict__ emb,
    const float* __restrict__ w_ih0, float* __restrict__ gemb)
{
    __shared__ float As[64][36];   // [row][k]  +pad
    __shared__ float Bs[64][37];   // [n][k]    +pad (2-way conflicts only)
    __shared__ int   tok_s[64];

    const int tid = threadIdx.x;
    const int rt = blockIdx.x * 64;     // row tile: r = b*64 + t
    const int ct = blockIdx.y * 64;     // col tile: n
    const int tx = tid & 15;
    const int ty = tid >> 4;

    if (tid < 64) tok_s[tid] = tgt[rt + tid];
    __syncthreads();

    float acc[4][4] = {{0.f}};

    for (int jc = 0; jc < 512; jc += 32) {
        #pragma unroll
        for (int i = 0; i < 2; ++i) {
            int s2  = tid + i * 256;
            int row = s2 >> 3, kq = s2 & 7;
            *(float4*)&As[row][kq * 4] =
                *(const float4*)(emb + (size_t)tok_s[row] * E_ + jc + kq * 4);
        }
        #pragma unroll
        for (int i = 0; i < 2; ++i) {
            int s2 = tid + i * 256;
            int n  = s2 >> 3, kq = s2 & 7;
            *(float4*)&Bs[n][kq * 4] =
                *(const float4*)(w_ih0 + (size_t)(ct + n) * 1536 + jc + kq * 4);
        }
        __syncthreads();

        #pragma unroll
        for (int kk = 0; kk < 32; ++kk) {
            float a0 = As[ty * 4 + 0][kk], a1 = As[ty * 4 + 1][kk];
            float a2 = As[ty * 4 + 2][kk], a3 = As[ty * 4 + 3][kk];
            float b0 = Bs[tx * 4 + 0][kk], b1 = Bs[tx * 4 + 1][kk];
            float b2 = Bs[tx * 4 + 2][kk], b3 = Bs[tx * 4 + 3][kk];
            acc[0][0] += a0 * b0; acc[0][1] += a0 * b1; acc[0][2] += a0 * b2; acc[0][3] += a0 * b3;
            acc[1][0] += a1 * b0; acc[1][1] += a1 * b1; acc[1][2] += a1 * b2; acc[1][3] += a1 * b3;
            acc[2][0] += a2 * b0; acc[2][1] += a2 * b1; acc[2][2] += a2 * b2; acc[2][3] += a2 * b3;
            acc[3][0] += a3 * b0; acc[3][1] += a3 * b1; acc[3][2] += a3 * b2; acc[3][3] += a3 * b3;
        }
        __syncthreads();
    }

    #pragma unroll
    for (int i = 0; i < 4; ++i) {
        float4 v = make_float4(acc[i][0], acc[i][1], acc[i][2], acc[i][3]);
        *(float4*)(gemb + (size_t)(rt + ty * 4 + i) * 4096 + ct + tx * 4) = v;
    }
}

// ===========================================================================
// Round-2 GEMM skeleton (proven): grid 512, block 256 = 32 b x 2 jl x 4 ks.
// ===========================================================================

// -------- LSTM layer 0 (emb-gates hoisted): K = 2048 = [feed | h0] ---------
__global__ __launch_bounds__(256) void k_lstm0g(
    const float* __restrict__ gemb,
    const float* __restrict__ w_ih0, const float* __restrict__ w_hh0,
    const float* __restrict__ b_ih0, const float* __restrict__ b_hh0,
    const float* __restrict__ feed, const float* __restrict__ h0c,
    const float* __restrict__ c0c,
    float* __restrict__ h0n, float* __restrict__ c0n, int t)
{
    __shared__ float As[4][32][68];
    __shared__ float red[3][64][4];

    int tid = threadIdx.x;
    int b  = tid & 31;
    int jl = (tid >> 5) & 1;
    int ks = tid >> 6;
    int j  = blockIdx.x * 2 + jl;

    float acc0, acc1, acc2, acc3;
    if (ks == 0) {
        const float* ge = gemb + ((size_t)b * 64 + t) * 4096;
        acc0 = b_ih0[0 * H_ + j] + b_hh0[0 * H_ + j] + ge[0 * H_ + j];
        acc1 = b_ih0[1 * H_ + j] + b_hh0[1 * H_ + j] + ge[1 * H_ + j];
        acc2 = b_ih0[2 * H_ + j] + b_hh0[2 * H_ + j] + ge[2 * H_ + j];
        acc3 = b_ih0[3 * H_ + j] + b_hh0[3 * H_ + j] + ge[3 * H_ + j];
    } else {
        acc0 = acc1 = acc2 = acc3 = 0.0f;
    }

    for (int c = 0; c < 8; ++c) {
        #pragma unroll
        for (int i = 0; i < 8; ++i) {
            int q   = tid + i * 256;
            int ksq = q >> 9;
            int rem = q & 511;
            int bb  = rem >> 4;
            int kq  = rem & 15;
            int kg  = ksq * 512 + c * 64 + kq * 4;
            const float* src = (kg < 1024) ? (feed + (size_t)bb * H_ + kg)
                                           : (h0c + (size_t)bb * H_ + (kg - 1024));
            *(float4*)&As[ksq][bb][kq * 4] = *(const float4*)src;
        }
        __syncthreads();

        int kbase = ks * 512 + c * 64;
        const float4 *w0, *w1, *w2, *w3;
        if (kbase < 1024) {   // feed segment: w_ih0 cols [512, 1536)
            w0 = (const float4*)(w_ih0 + (size_t)(0 * H_ + j) * 1536 + 512 + kbase);
            w1 = (const float4*)(w_ih0 + (size_t)(1 * H_ + j) * 1536 + 512 + kbase);
            w2 = (const float4*)(w_ih0 + (size_t)(2 * H_ + j) * 1536 + 512 + kbase);
            w3 = (const float4*)(w_ih0 + (size_t)(3 * H_ + j) * 1536 + 512 + kbase);
        } else {              // h0 segment: w_hh0
            int kb = kbase - 1024;
            w0 = (const float4*)(w_hh0 + (size_t)(0 * H_ + j) * 1024 + kb);
            w1 = (const float4*)(w_hh0 + (size_t)(1 * H_ + j) * 1024 + kb);
            w2 = (const float4*)(w_hh0 + (size_t)(2 * H_ + j) * 1024 + kb);
            w3 = (const float4*)(w_hh0 + (size_t)(3 * H_ + j) * 1024 + kb);
        }
        const float4* A4 = (const float4*)&As[ks][b][0];
        #pragma unroll
        for (int kk = 0; kk < 16; ++kk) {
            float4 a  = A4[kk];
            float4 q0 = w0[kk], q1 = w1[kk], q2 = w2[kk], q3 = w3[kk];
            acc0 += a.x * q0.x + a.y * q0.y + a.z * q0.z + a.w * q0.w;
            acc1 += a.x * q1.x + a.y * q1.y + a.z * q1.z + a.w * q1.w;
            acc2 += a.x * q2.x + a.y * q2.y + a.z * q2.z + a.w * q2.w;
            acc3 += a.x * q3.x + a.y * q3.y + a.z * q3.z + a.w * q3.w;
        }
        __syncthreads();
    }

    int idx = tid & 63;
    if (ks > 0) {
        red[ks - 1][idx][0] = acc0; red[ks - 1][idx][1] = acc1;
        red[ks - 1][idx][2] = acc2; red[ks - 1][idx][3] = acc3;
    }
    __syncthreads();
    if (ks == 0) {
        #pragma unroll
        for (int r = 0; r < 3; ++r) {
            acc0 += red[r][idx][0]; acc1 += red[r][idx][1];
            acc2 += red[r][idx][2]; acc3 += red[r][idx][3];
        }
        float co = c0c[b * H_ + j];
        float cn = sigm(acc1) * co + sigm(acc0) * tanh_(acc2);
        float hn = sigm(acc3) * tanh_(cn);
        c0n[b * H_ + j] = cn;
        h0n[b * H_ + j] = hn;
    }
}

// -------- LSTM layer 0 (fallback, K = 2560 with in-loop emb gather) --------
__global__ __launch_bounds__(256) void k_lstm0(
    const int* __restrict__ tgt, const float* __restrict__ emb,
    const float* __restrict__ w_ih0, const float* __restrict__ w_hh0,
    const float* __restrict__ b_ih0, const float* __restrict__ b_hh0,
    const float* __restrict__ feed, const float* __restrict__ h0c,
    const float* __restrict__ c0c,
    float* __restrict__ h0n, float* __restrict__ c0n, int t)
{
    __shared__ float As[4][32][68];
    __shared__ float red[3][64][4];
    __shared__ int   tok[32];

    int tid = threadIdx.x;
    int b  = tid & 31;
    int jl = (tid >> 5) & 1;
    int ks = tid >> 6;
    int j  = blockIdx.x * 2 + jl;

    if (tid < 32) tok[tid] = tgt[tid * T_ + t];
    __syncthreads();

    float acc0, acc1, acc2, acc3;
    if (ks == 0) {
        acc0 = b_ih0[0 * H_ + j] + b_hh0[0 * H_ + j];
        acc1 = b_ih0[1 * H_ + j] + b_hh0[1 * H_ + j];
        acc2 = b_ih0[2 * H_ + j] + b_hh0[2 * H_ + j];
        acc3 = b_ih0[3 * H_ + j] + b_hh0[3 * H_ + j];
    } else {
        acc0 = acc1 = acc2 = acc3 = 0.0f;
    }

    for (int c = 0; c < 10; ++c) {
        #pragma unroll
        for (int i = 0; i < 8; ++i) {
            int q   = tid + i * 256;
            int ksq = q >> 9;
            int rem = q & 511;
            int bb  = rem >> 4;
            int kq  = rem & 15;
            int kg  = ksq * 640 + c * 64 + kq * 4;
            const float* src;
            if (kg < 512)        src = emb  + (size_t)tok[bb] * E_ + kg;
            else if (kg < 1536)  src = feed + (size_t)bb * H_ + (kg - 512);
            else                 src = h0c  + (size_t)bb * H_ + (kg - 1536);
            *(float4*)&As[ksq][bb][kq * 4] = *(const float4*)src;
        }
        __syncthreads();

        int kbase = ks * 640 + c * 64;
        const float4 *w0, *w1, *w2, *w3;
        if (kbase < 1536) {
            w0 = (const float4*)(w_ih0 + (size_t)(0 * H_ + j) * 1536 + kbase);
            w1 = (const float4*)(w_ih0 + (size_t)(1 * H_ + j) * 1536 + kbase);
            w2 = (const float4*)(w_ih0 + (size_t)(2 * H_ + j) * 1536 + kbase);
            w3 = (const float4*)(w_ih0 + (size_t)(3 * H_ + j) * 1536 + kbase);
        } else {
            int kb = kbase - 1536;
            w0 = (const float4*)(w_hh0 + (size_t)(0 * H_ + j) * 1024 + kb);
            w1 = (const float4*)(w_hh0 + (size_t)(1 * H_ + j) * 1024 + kb);
            w2 = (const float4*)(w_hh0 + (size_t)(2 * H_ + j) * 1024 + kb);
            w3 = (const float4*)(w_hh0 + (size_t)(3 * H_ + j) * 1024 + kb);
        }
        const float4* A4 = (const float4*)&As[ks][b][0];
        #pragma unroll
        for (int kk = 0; kk < 16; ++kk) {
            float4 a  = A4[kk];
            float4 q0 = w0[kk], q1 = w1[kk], q2 = w2[kk], q3 = w3[kk];
            acc0 += a.x * q0.x + a.y * q0.y + a.z * q0.z + a.w * q0.w;
            acc1 += a.x * q1.x + a.y * q1.y + a.z * q1.z + a.w * q1.w;
            acc2 += a.x * q2.x + a.y * q2.y + a.z * q2.z + a.w * q2.w;
            acc3 += a.x * q3.x + a.y * q3.y + a.z * q3.z + a.w * q3.w;
        }
        __syncthreads();
    }

    int idx = tid & 63;
    if (ks > 0) {
        red[ks - 1][idx][0] = acc0; red[ks - 1][idx][1] = acc1;
        red[ks - 1][idx][2] = acc2; red[ks - 1][idx][3] = acc3;
    }
    __syncthreads();
    if (ks == 0) {
        #pragma unroll
        for (int r = 0; r < 3; ++r) {
            acc0 += red[r][idx][0]; acc1 += red[r][idx][1];
            acc2 += red[r][idx][2]; acc3 += red[r][idx][3];
        }
        float co = c0c[b * H_ + j];
        float cn = sigm(acc1) * co + sigm(acc0) * tanh_(acc2);
        float hn = sigm(acc3) * tanh_(cn);
        c0n[b * H_ + j] = cn;
        h0n[b * H_ + j] = hn;
    }
}

// -------- LSTM layer 1: K = 2048 = [h0n 1024 | h1 1024] --------------------
__global__ __launch_bounds__(256) void k_lstm1(
    const float* __restrict__ w_ih1, const float* __restrict__ w_hh1,
    const float* __restrict__ b_ih1, const float* __restrict__ b_hh1,
    const float* __restrict__ x, const float* __restrict__ h1c,
    const float* __restrict__ c1c,
    float* __restrict__ h1n, float* __restrict__ c1n)
{
    __shared__ float As[4][32][68];
    __shared__ float red[3][64][4];

    int tid = threadIdx.x;
    int b  = tid & 31;
    int jl = (tid >> 5) & 1;
    int ks = tid >> 6;
    int j  = blockIdx.x * 2 + jl;

    float acc0, acc1, acc2, acc3;
    if (ks == 0) {
        acc0 = b_ih1[0 * H_ + j] + b_hh1[0 * H_ + j];
        acc1 = b_ih1[1 * H_ + j] + b_hh1[1 * H_ + j];
        acc2 = b_ih1[2 * H_ + j] + b_hh1[2 * H_ + j];
        acc3 = b_ih1[3 * H_ + j] + b_hh1[3 * H_ + j];
    } else {
        acc0 = acc1 = acc2 = acc3 = 0.0f;
    }

    for (int c = 0; c < 8; ++c) {
        #pragma unroll
        for (int i = 0; i < 8; ++i) {
            int q   = tid + i * 256;
            int ksq = q >> 9;
            int rem = q & 511;
            int bb  = rem >> 4;
            int kq  = rem & 15;
            int kg  = ksq * 512 + c * 64 + kq * 4;
            const float* src = (kg < 1024) ? (x + (size_t)bb * H_ + kg)
                                           : (h1c + (size_t)bb * H_ + (kg - 1024));
            *(float4*)&As[ksq][bb][kq * 4] = *(const float4*)src;
        }
        __syncthreads();

        int kbase = ks * 512 + c * 64;
        const float* wb;
        int ko;
        if (kbase < 1024) { wb = w_ih1; ko = kbase; }
        else              { wb = w_hh1; ko = kbase - 1024; }
        const float4* w0 = (const float4*)(wb + (size_t)(0 * H_ + j) * H_ + ko);
        const float4* w1 = (const float4*)(wb + (size_t)(1 * H_ + j) * H_ + ko);
        const float4* w2 = (const float4*)(wb + (size_t)(2 * H_ + j) * H_ + ko);
        const float4* w3 = (const float4*)(wb + (size_t)(3 * H_ + j) * H_ + ko);
        const float4* A4 = (const float4*)&As[ks][b][0];
        #pragma unroll
        for (int kk = 0; kk < 16; ++kk) {
            float4 a  = A4[kk];
            float4 q0 = w0[kk], q1 = w1[kk], q2 = w2[kk], q3 = w3[kk];
            acc0 += a.x * q0.x + a.y * q0.y + a.z * q0.z + a.w * q0.w;
            acc1 += a.x * q1.x + a.y * q1.y + a.z * q1.z + a.w * q1.w;
            acc2 += a.x * q2.x + a.y * q2.y + a.z * q2.z + a.w * q2.w;
            acc3 += a.x * q3.x + a.y * q3.y + a.z * q3.z + a.w * q3.w;
        }
        __syncthreads();
    }

    int idx = tid & 63;
    if (ks > 0) {
        red[ks - 1][idx][0] = acc0; red[ks - 1][idx][1] = acc1;
        red[ks - 1][idx][2] = acc2; red[ks - 1][idx][3] = acc3;
    }
    __syncthreads();
    if (ks == 0) {
        #pragma unroll
        for (int r = 0; r < 3; ++r) {
            acc0 += red[r][idx][0]; acc1 += red[r][idx][1];
            acc2 += red[r][idx][2]; acc3 += red[r][idx][3];
        }
        float co = c1c[b * H_ + j];
        float cn = sigm(acc1) * co + sigm(acc0) * tanh_(acc2);
        float hn = sigm(acc3) * tanh_(cn);
        c1n[b * H_ + j] = cn;
        h1n[b * H_ + j] = hn;
    }
}

// -------- q = h1n @ w_in^T (minimal-tier fallback only) --------------------
__global__ __launch_bounds__(256) void k_q(
    const float* __restrict__ w_in, const float* __restrict__ h1n,
    float* __restrict__ q_out)
{
    __shared__ float As[4][32][68];
    __shared__ float red[3][64];

    int tid = threadIdx.x;
    int b  = tid & 31;
    int jl = (tid >> 5) & 1;
    int ks = tid >> 6;
    int j  = blockIdx.x * 2 + jl;

    float acc = 0.0f;
    for (int c = 0; c < 4; ++c) {
        #pragma unroll
        for (int i = 0; i < 8; ++i) {
            int q   = tid + i * 256;
            int ksq = q >> 9;
            int rem = q & 511;
            int bb  = rem >> 4;
            int kq  = rem & 15;
            int kg  = ksq * 256 + c * 64 + kq * 4;
            *(float4*)&As[ksq][bb][kq * 4] = *(const float4*)(h1n + (size_t)bb * H_ + kg);
        }
        __syncthreads();

        int kbase = ks * 256 + c * 64;
        const float4* w0 = (const float4*)(w_in + (size_t)j * H_ + kbase);
        const float4* A4 = (const float4*)&As[ks][b][0];
        #pragma unroll
        for (int kk = 0; kk < 16; ++kk) {
            float4 a  = A4[kk];
            float4 q0 = w0[kk];
            acc += a.x * q0.x + a.y * q0.y + a.z * q0.z + a.w * q0.w;
        }
        __syncthreads();
    }

    int idx = tid & 63;
    if (ks > 0) red[ks - 1][idx] = acc;
    __syncthreads();
    if (ks == 0) {
        acc += red[0][idx] + red[1][idx] + red[2][idx];
        q_out[b * H_ + j] = acc;
    }
}

// ---------------------------------------------------------------------------
// scores[b][s] = x[b] . base[b][s]   grid 512 = b(32) x stile(16), block 256.
// ---------------------------------------------------------------------------
__global__ __launch_bounds__(256) void k_scores(
    const float* __restrict__ x_in, const float* __restrict__ base,
    float* __restrict__ sc_out)
{
    __shared__ float q_lds[1024];

    int b  = blockIdx.x >> 4;
    int st = blockIdx.x & 15;
    int tid  = threadIdx.x;
    int lane = tid & 63;
    int wv   = tid >> 6;

    ((float4*)q_lds)[tid] = ((const float4*)(x_in + (size_t)b * H_))[tid];
    __syncthreads();

    float4 q4[4];
    #pragma unroll
    for (int i = 0; i < 4; ++i) q4[i] = ((const float4*)q_lds)[lane + 64 * i];

    const float* mb = base + (size_t)b * S_ * H_;
    #pragma unroll
    for (int ss = 0; ss < 4; ++ss) {
        int s = st * 16 + wv * 4 + ss;
        const float4* mr = (const float4*)(mb + (size_t)s * H_);
        float a = 0.0f;
        #pragma unroll
        for (int i = 0; i < 4; ++i) {
            float4 m = mr[lane + 64 * i];
            a += q4[i].x * m.x + q4[i].y * m.y + q4[i].z * m.z + q4[i].w * m.w;
        }
        #pragma unroll
        for (int o = 32; o > 0; o >>= 1) a += __shfl_down(a, o);
        if (lane == 0) sc_out[b * S_ + s] = a;
    }
}

// ---------------------------------------------------------------------------
// ctx: local masked softmax of scores + weighted sum.  grid 512, block 256
// ---------------------------------------------------------------------------
__global__ __launch_bounds__(256) void k_ctx(
    const float* __restrict__ sc_in, const float* __restrict__ mem,
    const int* __restrict__ masks,
    float* __restrict__ ctx, float* __restrict__ attn_out, int t)
{
    __shared__ float aw[256];
    __shared__ float red2[4][64];

    int b  = blockIdx.x >> 4;
    int ht = blockIdx.x & 15;
    int tid  = threadIdx.x;
    int lane = tid & 63;
    int wv   = tid >> 6;

    if (wv == 0) {
        int m = 0;
        #pragma unroll
        for (int i = 0; i < 4; ++i) m += masks[b * S_ + lane * 4 + i];
        #pragma unroll
        for (int o = 32; o > 0; o >>= 1) m += __shfl_down(m, o);
        int len = __shfl(m, 0);

        float v[4];
        float mx = -1e30f;
        #pragma unroll
        for (int i = 0; i < 4; ++i) {
            int s = lane + 64 * i;
            float xv = (s < len) ? sc_in[b * S_ + s] : -1e9f;
            v[i] = xv;
            mx = fmaxf(mx, xv);
        }
        #pragma unroll
        for (int o = 32; o > 0; o >>= 1) mx = fmaxf(mx, __shfl_xor(mx, o));
        float sm = 0.0f;
        #pragma unroll
        for (int i = 0; i < 4; ++i) { v[i] = __expf(v[i] - mx); sm += v[i]; }
        #pragma unroll
        for (int o = 32; o > 0; o >>= 1) sm += __shfl_xor(sm, o);
        float inv = 1.0f / sm;
        #pragma unroll
        for (int i = 0; i < 4; ++i) {
            int s = lane + 64 * i;
            float w = v[i] * inv;
            aw[s] = w;
            if (ht == 0) attn_out[((size_t)b * T_ + t) * S_ + s] = w;
        }
    }
    __syncthreads();

    int h = ht * 64 + lane;
    const float* mb = mem + (size_t)b * S_ * H_;
    float a = 0.0f;
    #pragma unroll 8
    for (int ss = 0; ss < 64; ++ss) {
        int s = wv * 64 + ss;
        a += aw[s] * mb[(size_t)s * H_ + h];
    }
    red2[wv][lane] = a;
    __syncthreads();
    if (tid < 64) {
        float r = red2[0][tid] + red2[1][tid] + red2[2][tid] + red2[3][tid];
        ctx[b * H_ + ht * 64 + tid] = r;
    }
}

// -------- out = tanh([ctx | h1n] @ w_out^T) --------------------------------
__global__ __launch_bounds__(256) void k_out(
    const float* __restrict__ w_out, const float* __restrict__ ctx,
    const float* __restrict__ h1n,
    float* __restrict__ feedn, float* __restrict__ dout, int t)
{
    __shared__ float As[4][32][68];
    __shared__ float red[3][64];

    int tid = threadIdx.x;
    int b  = tid & 31;
    int jl = (tid >> 5) & 1;
    int ks = tid >> 6;
    int j  = blockIdx.x * 2 + jl;

    float acc = 0.0f;
    for (int c = 0; c < 8; ++c) {
        #pragma unroll
        for (int i = 0; i < 8; ++i) {
            int q   = tid + i * 256;
            int ksq = q >> 9;
            int rem = q & 511;
            int bb  = rem >> 4;
            int kq  = rem & 15;
            int kg  = ksq * 512 + c * 64 + kq * 4;
            const float* src = (kg < 1024) ? (ctx + (size_t)bb * H_ + kg)
                                           : (h1n + (size_t)bb * H_ + (kg - 1024));
            *(float4*)&As[ksq][bb][kq * 4] = *(const float4*)src;
        }
        __syncthreads();

        int kbase = ks * 512 + c * 64;
        const float4* w0 = (const float4*)(w_out + (size_t)j * 2048 + kbase);
        const float4* A4 = (const float4*)&As[ks][b][0];
        #pragma unroll
        for (int kk = 0; kk < 16; ++kk) {
            float4 a  = A4[kk];
            float4 q0 = w0[kk];
            acc += a.x * q0.x + a.y * q0.y + a.z * q0.z + a.w * q0.w;
        }
        __syncthreads();
    }

    int idx = tid & 63;
    if (ks > 0) red[ks - 1][idx] = acc;
    __syncthreads();
    if (ks == 0) {
        acc += red[0][idx] + red[1][idx] + red[2][idx];
        float o = tanh_(acc);
        feedn[b * H_ + j] = o;
        dout[((size_t)b * T_ + t) * H_ + j] = o;
    }
}

// ---------------------------------------------------------------------------
extern "C" void kernel_launch(void* const* d_in, const int* in_sizes, int n_in,
                              void* d_out, int out_size, void* d_ws, size_t ws_size,
                              hipStream_t stream) {
    const int*   tgt    = (const int*)  d_in[0];
    const float* mem    = (const float*)d_in[1];
    const int*   masks  = (const int*)  d_in[2];
    const float* h0in   = (const float*)d_in[3];
    const float* c0in   = (const float*)d_in[4];
    const float* emb    = (const float*)d_in[5];
    const float* w_ih0  = (const float*)d_in[6];
    const float* w_hh0  = (const float*)d_in[7];
    const float* b_ih0  = (const float*)d_in[8];
    const float* b_hh0  = (const float*)d_in[9];
    const float* w_ih1  = (const float*)d_in[10];
    const float* w_hh1  = (const float*)d_in[11];
    const float* b_ih1  = (const float*)d_in[12];
    const float* b_hh1  = (const float*)d_in[13];
    const float* w_in   = (const float*)d_in[14];
    const float* w_out  = (const float*)d_in[15];

    float* dout     = (float*)d_out;
    float* attn_out = dout + (size_t)B_ * T_ * H_;

    float* ws   = (float*)d_ws;
    float* h0s  = ws;              // [2][B*H]
    float* c0s  = h0s  + 2 * BH_;  // [2][B*H]
    float* h1s  = c0s  + 2 * BH_;  // [2][B*H]
    float* c1s  = h1s  + 2 * BH_;  // [2][B*H]
    float* feed = c1s  + 2 * BH_;  // [2][B*H]
    float* qctx = feed + 2 * BH_;  // [B*H]
    float* scw  = qctx + BH_;      // [B*S]
    float* pmem = scw  + B_ * S_;  // [B*S*H]   33.5 MB
    float* gemb = pmem + (size_t)B_ * S_ * H_;   // [B*T*4096]  33.5 MB

    const size_t base_fl = (size_t)11 * BH_ + B_ * S_;
    const size_t needA = (base_fl + (size_t)B_ * S_ * H_ + (size_t)B_ * T_ * 4096) * 4;
    const size_t needB = (base_fl + (size_t)B_ * S_ * H_) * 4;

    k_init<<<128, 256, 0, stream>>>(h0in, c0in, h0s, c0s, h1s, c1s, feed);

    if (ws_size >= needA) {
        // ---------- fast tier: pmem + emb-gates hoisted ----------
        k_pmem<<<dim3(128, 16), 256, 0, stream>>>(mem, w_in, pmem);
        k_gemb<<<dim3(32, 64), 256, 0, stream>>>(tgt, emb, w_ih0, gemb);

        for (int t = 0; t < T_; ++t) {
            int cur = t & 1, nxt = cur ^ 1;
            k_lstm0g<<<512, 256, 0, stream>>>(gemb, w_ih0, w_hh0, b_ih0, b_hh0,
                                              feed + cur * BH_, h0s + cur * BH_, c0s + cur * BH_,
                                              h0s + nxt * BH_, c0s + nxt * BH_, t);
            k_lstm1<<<512, 256, 0, stream>>>(w_ih1, w_hh1, b_ih1, b_hh1,
                                             h0s + nxt * BH_, h1s + cur * BH_, c1s + cur * BH_,
                                             h1s + nxt * BH_, c1s + nxt * BH_);
            k_scores<<<512, 256, 0, stream>>>(h1s + nxt * BH_, pmem, scw);
            k_ctx<<<512, 256, 0, stream>>>(scw, mem, masks, qctx, attn_out, t);
            k_out<<<512, 256, 0, stream>>>(w_out, qctx, h1s + nxt * BH_,
                                           feed + nxt * BH_, dout, t);
        }
    } else if (ws_size >= needB) {
        // ---------- R7 champion tier ----------
        k_pmem<<<dim3(128, 16), 256, 0, stream>>>(mem, w_in, pmem);

        for (int t = 0; t < T_; ++t) {
            int cur = t & 1, nxt = cur ^ 1;
            k_lstm0<<<512, 256, 0, stream>>>(tgt, emb, w_ih0, w_hh0, b_ih0, b_hh0,
                                             feed + cur * BH_, h0s + cur * BH_, c0s + cur * BH_,
                                             h0s + nxt * BH_, c0s + nxt * BH_, t);
            k_lstm1<<<512, 256, 0, stream>>>(w_ih1, w_hh1, b_ih1, b_hh1,
                                             h0s + nxt * BH_, h1s + cur * BH_, c1s + cur * BH_,
                                             h1s + nxt * BH_, c1s + nxt * BH_);
            k_scores<<<512, 256, 0, stream>>>(h1s + nxt * BH_, pmem, scw);
            k_ctx<<<512, 256, 0, stream>>>(scw, mem, masks, qctx, attn_out, t);
            k_out<<<512, 256, 0, stream>>>(w_out, qctx, h1s + nxt * BH_,
                                           feed + nxt * BH_, dout, t);
        }
    } else {
        // ---------- minimal tier (round-2) ----------
        for (int t = 0; t < T_; ++t) {
            int cur = t & 1, nxt = cur ^ 1;
            k_lstm0<<<512, 256, 0, stream>>>(tgt, emb, w_ih0, w_hh0, b_ih0, b_hh0,
                                             feed + cur * BH_, h0s + cur * BH_, c0s + cur * BH_,
                                             h0s + nxt * BH_, c0s + nxt * BH_, t);
            k_lstm1<<<512, 256, 0, stream>>>(w_ih1, w_hh1, b_ih1, b_hh1,
                                             h0s + nxt * BH_, h1s + cur * BH_, c1s + cur * BH_,
                                             h1s + nxt * BH_, c1s + nxt * BH_);
            k_q<<<512, 256, 0, stream>>>(w_in, h1s + nxt * BH_, qctx);
            k_scores<<<512, 256, 0, stream>>>(qctx, mem, scw);
            k_ctx<<<512, 256, 0, stream>>>(scw, mem, masks, qctx, attn_out, t);
            k_out<<<512, 256, 0, stream>>>(w_out, qctx, h1s + nxt * BH_,
                                           feed + nxt * BH_, dout, t);
        }
    }
}

// Round 14
// 5832.629 us; speedup vs baseline: 1.5124x; 1.3192x over previous
//
#include <hip/hip_runtime.h>
#include <math.h>

#define B_ 32
#define T_ 64
#define S_ 256
#define H_ 1024
#define E_ 512
#define BH_ (B_ * H_)

__device__ __forceinline__ float sigm(float x) {
    return 1.0f / (1.0f + __expf(-x));
}
__device__ __forceinline__ float tanh_(float x) {
    x = fminf(15.0f, fmaxf(-15.0f, x));
    float e = __expf(-2.0f * x);
    return (1.0f - e) / (1.0f + e);
}

// ---------------------------------------------------------------------------
// init: state ping-pong slot 0 + zero input feed
// ---------------------------------------------------------------------------
__global__ void k_init(const float* __restrict__ h0in, const float* __restrict__ c0in,
                       float* h0s, float* c0s, float* h1s, float* c1s, float* feed) {
    int i = blockIdx.x * 256 + threadIdx.x;
    if (i < BH_) {
        h0s[i]  = h0in[i];
        h1s[i]  = h0in[BH_ + i];
        c0s[i]  = c0in[i];
        c1s[i]  = c0in[BH_ + i];
        feed[i] = 0.0f;
    }
}

// ---------------------------------------------------------------------------
// pmem[r][k] = sum_j mem[r][j] * w_in[j][k]   (time-invariant; R7-proven)
// ---------------------------------------------------------------------------
__global__ __launch_bounds__(256) void k_pmem(
    const float* __restrict__ mem, const float* __restrict__ w_in,
    float* __restrict__ pmem)
{
    __shared__ float As[64][36];
    __shared__ float Bs[32][68];

    const int tid = threadIdx.x;
    const int rt = blockIdx.x * 64;
    const int ct = blockIdx.y * 64;
    const int tx = tid & 15;
    const int ty = tid >> 4;

    float acc[4][4] = {{0.f}};

    for (int jc = 0; jc < 1024; jc += 32) {
        #pragma unroll
        for (int i = 0; i < 2; ++i) {
            int s2  = tid + i * 256;
            int row = s2 >> 3, kq = s2 & 7;
            *(float4*)&As[row][kq * 4] =
                *(const float4*)(mem + (size_t)(rt + row) * 1024 + jc + kq * 4);
        }
        #pragma unroll
        for (int i = 0; i < 2; ++i) {
            int s2 = tid + i * 256;
            int kk = s2 >> 4, cq = s2 & 15;
            *(float4*)&Bs[kk][cq * 4] =
                *(const float4*)(w_in + (size_t)(jc + kk) * 1024 + ct + cq * 4);
        }
        __syncthreads();

        #pragma unroll
        for (int kk = 0; kk < 32; ++kk) {
            float a0 = As[ty * 4 + 0][kk], a1 = As[ty * 4 + 1][kk];
            float a2 = As[ty * 4 + 2][kk], a3 = As[ty * 4 + 3][kk];
            float b0 = Bs[kk][tx * 4 + 0], b1 = Bs[kk][tx * 4 + 1];
            float b2 = Bs[kk][tx * 4 + 2], b3 = Bs[kk][tx * 4 + 3];
            acc[0][0] += a0 * b0; acc[0][1] += a0 * b1; acc[0][2] += a0 * b2; acc[0][3] += a0 * b3;
            acc[1][0] += a1 * b0; acc[1][1] += a1 * b1; acc[1][2] += a1 * b2; acc[1][3] += a1 * b3;
            acc[2][0] += a2 * b0; acc[2][1] += a2 * b1; acc[2][2] += a2 * b2; acc[2][3] += a2 * b3;
            acc[3][0] += a3 * b0; acc[3][1] += a3 * b1; acc[3][2] += a3 * b2; acc[3][3] += a3 * b3;
        }
        __syncthreads();
    }

    #pragma unroll
    for (int i = 0; i < 4; ++i) {
        float4 v = make_float4(acc[i][0], acc[i][1], acc[i][2], acc[i][3]);
        *(float4*)(pmem + (size_t)(rt + ty * 4 + i) * 1024 + ct + tx * 4) = v;
    }
}

// ---------------------------------------------------------------------------
// gemb[r][n] = sum_k emb[tgt[r]][k] * w_ih0[n][k]   (r = b*64+t; K = 512)
// ---------------------------------------------------------------------------
__global__ __launch_bounds__(256) void k_gemb(
    const int* __restrict__ tgt, const float* __restrict__ emb,
    const float* __restrict__ w_ih0, float* __restrict__ gemb)
{
    __shared__ float As[64][36];
    __shared__ float Bs[64][37];
    __shared__ int   tok_s[64];

    const int tid = threadIdx.x;
    const int rt = blockIdx.x * 64;
    const int ct = blockIdx.y * 64;
    const int tx = tid & 15;
    const int ty = tid >> 4;

    if (tid < 64) tok_s[tid] = tgt[rt + tid];
    __syncthreads();

    float acc[4][4] = {{0.f}};

    for (int jc = 0; jc < 512; jc += 32) {
        #pragma unroll
        for (int i = 0; i < 2; ++i) {
            int s2  = tid + i * 256;
            int row = s2 >> 3, kq = s2 & 7;
            *(float4*)&As[row][kq * 4] =
                *(const float4*)(emb + (size_t)tok_s[row] * E_ + jc + kq * 4);
        }
        #pragma unroll
        for (int i = 0; i < 2; ++i) {
            int s2 = tid + i * 256;
            int n  = s2 >> 3, kq = s2 & 7;
            *(float4*)&Bs[n][kq * 4] =
                *(const float4*)(w_ih0 + (size_t)(ct + n) * 1536 + jc + kq * 4);
        }
        __syncthreads();

        #pragma unroll
        for (int kk = 0; kk < 32; ++kk) {
            float a0 = As[ty * 4 + 0][kk], a1 = As[ty * 4 + 1][kk];
            float a2 = As[ty * 4 + 2][kk], a3 = As[ty * 4 + 3][kk];
            float b0 = Bs[tx * 4 + 0][kk], b1 = Bs[tx * 4 + 1][kk];
            float b2 = Bs[tx * 4 + 2][kk], b3 = Bs[tx * 4 + 3][kk];
            acc[0][0] += a0 * b0; acc[0][1] += a0 * b1; acc[0][2] += a0 * b2; acc[0][3] += a0 * b3;
            acc[1][0] += a1 * b0; acc[1][1] += a1 * b1; acc[1][2] += a1 * b2; acc[1][3] += a1 * b3;
            acc[2][0] += a2 * b0; acc[2][1] += a2 * b1; acc[2][2] += a2 * b2; acc[2][3] += a2 * b3;
            acc[3][0] += a3 * b0; acc[3][1] += a3 * b1; acc[3][2] += a3 * b2; acc[3][3] += a3 * b3;
        }
        __syncthreads();
    }

    #pragma unroll
    for (int i = 0; i < 4; ++i) {
        float4 v = make_float4(acc[i][0], acc[i][1], acc[i][2], acc[i][3]);
        *(float4*)(gemb + (size_t)(rt + ty * 4 + i) * 4096 + ct + tx * 4) = v;
    }
}

// ---------------------------------------------------------------------------
// k_gates: part[ks][b][n] = sum_{k in ks-slice} A[b][k] * W[n][k]
// A = [a0 (k<1024) | a1 (k>=1024)], W row n: wa (k<1024, ld=lda) / wb (ld=ldb).
// grid (64 ntiles, 8 ksplit), block 256 = 16tx x 16ty.  Tile 32b x 64n,
// K-chunk 32, per-thread 2b x 4n register tile (k_gemb-shaped; coalesced W).
// ---------------------------------------------------------------------------
__global__ __launch_bounds__(256) void k_gates(
    const float* __restrict__ a0, const float* __restrict__ a1,
    const float* __restrict__ wa, int lda,
    const float* __restrict__ wb, int ldb,
    float* __restrict__ part)
{
    __shared__ float As[32][33];
    __shared__ float Bs[64][33];

    const int tid = threadIdx.x;
    const int nt = blockIdx.x;
    const int ks = blockIdx.y;
    const int tx = tid & 15;
    const int ty = tid >> 4;

    const int k0 = ks * 256;
    const bool hi = (k0 >= 1024);
    const float* a   = hi ? a1 : a0;
    const float* w   = hi ? wb : wa;
    const int    ldw = hi ? ldb : lda;
    const int    ko  = hi ? (k0 - 1024) : k0;

    float acc[2][4] = {{0.f, 0.f, 0.f, 0.f}, {0.f, 0.f, 0.f, 0.f}};

    for (int c = 0; c < 8; ++c) {
        {   // A: 32 b x 32 k, 1 float4/thread
            int row = tid >> 3, kq = tid & 7;
            float4 v = *(const float4*)(a + (size_t)row * H_ + ko + c * 32 + kq * 4);
            As[row][kq * 4 + 0] = v.x; As[row][kq * 4 + 1] = v.y;
            As[row][kq * 4 + 2] = v.z; As[row][kq * 4 + 3] = v.w;
        }
        #pragma unroll
        for (int i = 0; i < 2; ++i) {   // W: 64 n x 32 k
            int s2 = tid + i * 256;
            int n = s2 >> 3, kq = s2 & 7;
            float4 v = *(const float4*)(w + (size_t)(nt * 64 + n) * ldw + ko + c * 32 + kq * 4);
            Bs[n][kq * 4 + 0] = v.x; Bs[n][kq * 4 + 1] = v.y;
            Bs[n][kq * 4 + 2] = v.z; Bs[n][kq * 4 + 3] = v.w;
        }
        __syncthreads();

        #pragma unroll
        for (int kk = 0; kk < 32; ++kk) {
            float av0 = As[ty * 2 + 0][kk];
            float av1 = As[ty * 2 + 1][kk];
            float b0 = Bs[tx * 4 + 0][kk], b1 = Bs[tx * 4 + 1][kk];
            float b2 = Bs[tx * 4 + 2][kk], b3 = Bs[tx * 4 + 3][kk];
            acc[0][0] += av0 * b0; acc[0][1] += av0 * b1;
            acc[0][2] += av0 * b2; acc[0][3] += av0 * b3;
            acc[1][0] += av1 * b0; acc[1][1] += av1 * b1;
            acc[1][2] += av1 * b2; acc[1][3] += av1 * b3;
        }
        __syncthreads();
    }

    #pragma unroll
    for (int r = 0; r < 2; ++r) {
        int b = ty * 2 + r;
        float4 v = make_float4(acc[r][0], acc[r][1], acc[r][2], acc[r][3]);
        *(float4*)(part + ((size_t)ks * 32 + b) * 4096 + nt * 64 + tx * 4) = v;
    }
}

// ---------------------------------------------------------------------------
// k_cell: sum 8 k-split partials + biases (+ gemb for layer 0), apply LSTM
// cell.  grid 128, block 256; one (b, j) per thread, coalesced along j.
// ---------------------------------------------------------------------------
__global__ __launch_bounds__(256) void k_cell(
    const float* __restrict__ part,
    const float* __restrict__ b_ih, const float* __restrict__ b_hh,
    const float* __restrict__ ge, int has_ge,
    const float* __restrict__ c_cur, float* __restrict__ c_nxt,
    float* __restrict__ h_nxt, int t)
{
    int idx = blockIdx.x * 256 + threadIdx.x;   // 0..32767
    int b = idx >> 10;
    int j = idx & 1023;

    float g0 = b_ih[0 * H_ + j] + b_hh[0 * H_ + j];
    float g1 = b_ih[1 * H_ + j] + b_hh[1 * H_ + j];
    float g2 = b_ih[2 * H_ + j] + b_hh[2 * H_ + j];
    float g3 = b_ih[3 * H_ + j] + b_hh[3 * H_ + j];
    if (has_ge) {
        const float* g = ge + ((size_t)b * 64 + t) * 4096;
        g0 += g[0 * H_ + j]; g1 += g[1 * H_ + j];
        g2 += g[2 * H_ + j]; g3 += g[3 * H_ + j];
    }
    #pragma unroll
    for (int p = 0; p < 8; ++p) {
        const float* pp = part + ((size_t)p * 32 + b) * 4096;
        g0 += pp[0 * H_ + j]; g1 += pp[1 * H_ + j];
        g2 += pp[2 * H_ + j]; g3 += pp[3 * H_ + j];
    }
    float co = c_cur[b * H_ + j];
    float cn = sigm(g1) * co + sigm(g0) * tanh_(g2);
    c_nxt[b * H_ + j] = cn;
    h_nxt[b * H_ + j] = sigm(g3) * tanh_(cn);
}

// ===========================================================================
// R13 fallback kernels (proven 7.69 ms tier)
// ===========================================================================
__global__ __launch_bounds__(256) void k_lstm0g(
    const float* __restrict__ gemb,
    const float* __restrict__ w_ih0, const float* __restrict__ w_hh0,
    const float* __restrict__ b_ih0, const float* __restrict__ b_hh0,
    const float* __restrict__ feed, const float* __restrict__ h0c,
    const float* __restrict__ c0c,
    float* __restrict__ h0n, float* __restrict__ c0n, int t)
{
    __shared__ float As[4][32][68];
    __shared__ float red[3][64][4];

    int tid = threadIdx.x;
    int b  = tid & 31;
    int jl = (tid >> 5) & 1;
    int ks = tid >> 6;
    int j  = blockIdx.x * 2 + jl;

    float acc0, acc1, acc2, acc3;
    if (ks == 0) {
        const float* ge = gemb + ((size_t)b * 64 + t) * 4096;
        acc0 = b_ih0[0 * H_ + j] + b_hh0[0 * H_ + j] + ge[0 * H_ + j];
        acc1 = b_ih0[1 * H_ + j] + b_hh0[1 * H_ + j] + ge[1 * H_ + j];
        acc2 = b_ih0[2 * H_ + j] + b_hh0[2 * H_ + j] + ge[2 * H_ + j];
        acc3 = b_ih0[3 * H_ + j] + b_hh0[3 * H_ + j] + ge[3 * H_ + j];
    } else {
        acc0 = acc1 = acc2 = acc3 = 0.0f;
    }

    for (int c = 0; c < 8; ++c) {
        #pragma unroll
        for (int i = 0; i < 8; ++i) {
            int q   = tid + i * 256;
            int ksq = q >> 9;
            int rem = q & 511;
            int bb  = rem >> 4;
            int kq  = rem & 15;
            int kg  = ksq * 512 + c * 64 + kq * 4;
            const float* src = (kg < 1024) ? (feed + (size_t)bb * H_ + kg)
                                           : (h0c + (size_t)bb * H_ + (kg - 1024));
            *(float4*)&As[ksq][bb][kq * 4] = *(const float4*)src;
        }
        __syncthreads();

        int kbase = ks * 512 + c * 64;
        const float4 *w0, *w1, *w2, *w3;
        if (kbase < 1024) {
            w0 = (const float4*)(w_ih0 + (size_t)(0 * H_ + j) * 1536 + 512 + kbase);
            w1 = (const float4*)(w_ih0 + (size_t)(1 * H_ + j) * 1536 + 512 + kbase);
            w2 = (const float4*)(w_ih0 + (size_t)(2 * H_ + j) * 1536 + 512 + kbase);
            w3 = (const float4*)(w_ih0 + (size_t)(3 * H_ + j) * 1536 + 512 + kbase);
        } else {
            int kb = kbase - 1024;
            w0 = (const float4*)(w_hh0 + (size_t)(0 * H_ + j) * 1024 + kb);
            w1 = (const float4*)(w_hh0 + (size_t)(1 * H_ + j) * 1024 + kb);
            w2 = (const float4*)(w_hh0 + (size_t)(2 * H_ + j) * 1024 + kb);
            w3 = (const float4*)(w_hh0 + (size_t)(3 * H_ + j) * 1024 + kb);
        }
        const float4* A4 = (const float4*)&As[ks][b][0];
        #pragma unroll
        for (int kk = 0; kk < 16; ++kk) {
            float4 a  = A4[kk];
            float4 q0 = w0[kk], q1 = w1[kk], q2 = w2[kk], q3 = w3[kk];
            acc0 += a.x * q0.x + a.y * q0.y + a.z * q0.z + a.w * q0.w;
            acc1 += a.x * q1.x + a.y * q1.y + a.z * q1.z + a.w * q1.w;
            acc2 += a.x * q2.x + a.y * q2.y + a.z * q2.z + a.w * q2.w;
            acc3 += a.x * q3.x + a.y * q3.y + a.z * q3.z + a.w * q3.w;
        }
        __syncthreads();
    }

    int idx = tid & 63;
    if (ks > 0) {
        red[ks - 1][idx][0] = acc0; red[ks - 1][idx][1] = acc1;
        red[ks - 1][idx][2] = acc2; red[ks - 1][idx][3] = acc3;
    }
    __syncthreads();
    if (ks == 0) {
        #pragma unroll
        for (int r = 0; r < 3; ++r) {
            acc0 += red[r][idx][0]; acc1 += red[r][idx][1];
            acc2 += red[r][idx][2]; acc3 += red[r][idx][3];
        }
        float co = c0c[b * H_ + j];
        float cn = sigm(acc1) * co + sigm(acc0) * tanh_(acc2);
        float hn = sigm(acc3) * tanh_(cn);
        c0n[b * H_ + j] = cn;
        h0n[b * H_ + j] = hn;
    }
}

__global__ __launch_bounds__(256) void k_lstm0(
    const int* __restrict__ tgt, const float* __restrict__ emb,
    const float* __restrict__ w_ih0, const float* __restrict__ w_hh0,
    const float* __restrict__ b_ih0, const float* __restrict__ b_hh0,
    const float* __restrict__ feed, const float* __restrict__ h0c,
    const float* __restrict__ c0c,
    float* __restrict__ h0n, float* __restrict__ c0n, int t)
{
    __shared__ float As[4][32][68];
    __shared__ float red[3][64][4];
    __shared__ int   tok[32];

    int tid = threadIdx.x;
    int b  = tid & 31;
    int jl = (tid >> 5) & 1;
    int ks = tid >> 6;
    int j  = blockIdx.x * 2 + jl;

    if (tid < 32) tok[tid] = tgt[tid * T_ + t];
    __syncthreads();

    float acc0, acc1, acc2, acc3;
    if (ks == 0) {
        acc0 = b_ih0[0 * H_ + j] + b_hh0[0 * H_ + j];
        acc1 = b_ih0[1 * H_ + j] + b_hh0[1 * H_ + j];
        acc2 = b_ih0[2 * H_ + j] + b_hh0[2 * H_ + j];
        acc3 = b_ih0[3 * H_ + j] + b_hh0[3 * H_ + j];
    } else {
        acc0 = acc1 = acc2 = acc3 = 0.0f;
    }

    for (int c = 0; c < 10; ++c) {
        #pragma unroll
        for (int i = 0; i < 8; ++i) {
            int q   = tid + i * 256;
            int ksq = q >> 9;
            int rem = q & 511;
            int bb  = rem >> 4;
            int kq  = rem & 15;
            int kg  = ksq * 640 + c * 64 + kq * 4;
            const float* src;
            if (kg < 512)        src = emb  + (size_t)tok[bb] * E_ + kg;
            else if (kg < 1536)  src = feed + (size_t)bb * H_ + (kg - 512);
            else                 src = h0c  + (size_t)bb * H_ + (kg - 1536);
            *(float4*)&As[ksq][bb][kq * 4] = *(const float4*)src;
        }
        __syncthreads();

        int kbase = ks * 640 + c * 64;
        const float4 *w0, *w1, *w2, *w3;
        if (kbase < 1536) {
            w0 = (const float4*)(w_ih0 + (size_t)(0 * H_ + j) * 1536 + kbase);
            w1 = (const float4*)(w_ih0 + (size_t)(1 * H_ + j) * 1536 + kbase);
            w2 = (const float4*)(w_ih0 + (size_t)(2 * H_ + j) * 1536 + kbase);
            w3 = (const float4*)(w_ih0 + (size_t)(3 * H_ + j) * 1536 + kbase);
        } else {
            int kb = kbase - 1536;
            w0 = (const float4*)(w_hh0 + (size_t)(0 * H_ + j) * 1024 + kb);
            w1 = (const float4*)(w_hh0 + (size_t)(1 * H_ + j) * 1024 + kb);
            w2 = (const float4*)(w_hh0 + (size_t)(2 * H_ + j) * 1024 + kb);
            w3 = (const float4*)(w_hh0 + (size_t)(3 * H_ + j) * 1024 + kb);
        }
        const float4* A4 = (const float4*)&As[ks][b][0];
        #pragma unroll
        for (int kk = 0; kk < 16; ++kk) {
            float4 a  = A4[kk];
            float4 q0 = w0[kk], q1 = w1[kk], q2 = w2[kk], q3 = w3[kk];
            acc0 += a.x * q0.x + a.y * q0.y + a.z * q0.z + a.w * q0.w;
            acc1 += a.x * q1.x + a.y * q1.y + a.z * q1.z + a.w * q1.w;
            acc2 += a.x * q2.x + a.y * q2.y + a.z * q2.z + a.w * q2.w;
            acc3 += a.x * q3.x + a.y * q3.y + a.z * q3.z + a.w * q3.w;
        }
        __syncthreads();
    }

    int idx = tid & 63;
    if (ks > 0) {
        red[ks - 1][idx][0] = acc0; red[ks - 1][idx][1] = acc1;
        red[ks - 1][idx][2] = acc2; red[ks - 1][idx][3] = acc3;
    }
    __syncthreads();
    if (ks == 0) {
        #pragma unroll
        for (int r = 0; r < 3; ++r) {
            acc0 += red[r][idx][0]; acc1 += red[r][idx][1];
            acc2 += red[r][idx][2]; acc3 += red[r][idx][3];
        }
        float co = c0c[b * H_ + j];
        float cn = sigm(acc1) * co + sigm(acc0) * tanh_(acc2);
        float hn = sigm(acc3) * tanh_(cn);
        c0n[b * H_ + j] = cn;
        h0n[b * H_ + j] = hn;
    }
}

__global__ __launch_bounds__(256) void k_lstm1(
    const float* __restrict__ w_ih1, const float* __restrict__ w_hh1,
    const float* __restrict__ b_ih1, const float* __restrict__ b_hh1,
    const float* __restrict__ x, const float* __restrict__ h1c,
    const float* __restrict__ c1c,
    float* __restrict__ h1n, float* __restrict__ c1n)
{
    __shared__ float As[4][32][68];
    __shared__ float red[3][64][4];

    int tid = threadIdx.x;
    int b  = tid & 31;
    int jl = (tid >> 5) & 1;
    int ks = tid >> 6;
    int j  = blockIdx.x * 2 + jl;

    float acc0, acc1, acc2, acc3;
    if (ks == 0) {
        acc0 = b_ih1[0 * H_ + j] + b_hh1[0 * H_ + j];
        acc1 = b_ih1[1 * H_ + j] + b_hh1[1 * H_ + j];
        acc2 = b_ih1[2 * H_ + j] + b_hh1[2 * H_ + j];
        acc3 = b_ih1[3 * H_ + j] + b_hh1[3 * H_ + j];
    } else {
        acc0 = acc1 = acc2 = acc3 = 0.0f;
    }

    for (int c = 0; c < 8; ++c) {
        #pragma unroll
        for (int i = 0; i < 8; ++i) {
            int q   = tid + i * 256;
            int ksq = q >> 9;
            int rem = q & 511;
            int bb  = rem >> 4;
            int kq  = rem & 15;
            int kg  = ksq * 512 + c * 64 + kq * 4;
            const float* src = (kg < 1024) ? (x + (size_t)bb * H_ + kg)
                                           : (h1c + (size_t)bb * H_ + (kg - 1024));
            *(float4*)&As[ksq][bb][kq * 4] = *(const float4*)src;
        }
        __syncthreads();

        int kbase = ks * 512 + c * 64;
        const float* wb;
        int ko;
        if (kbase < 1024) { wb = w_ih1; ko = kbase; }
        else              { wb = w_hh1; ko = kbase - 1024; }
        const float4* w0 = (const float4*)(wb + (size_t)(0 * H_ + j) * H_ + ko);
        const float4* w1 = (const float4*)(wb + (size_t)(1 * H_ + j) * H_ + ko);
        const float4* w2 = (const float4*)(wb + (size_t)(2 * H_ + j) * H_ + ko);
        const float4* w3 = (const float4*)(wb + (size_t)(3 * H_ + j) * H_ + ko);
        const float4* A4 = (const float4*)&As[ks][b][0];
        #pragma unroll
        for (int kk = 0; kk < 16; ++kk) {
            float4 a  = A4[kk];
            float4 q0 = w0[kk], q1 = w1[kk], q2 = w2[kk], q3 = w3[kk];
            acc0 += a.x * q0.x + a.y * q0.y + a.z * q0.z + a.w * q0.w;
            acc1 += a.x * q1.x + a.y * q1.y + a.z * q1.z + a.w * q1.w;
            acc2 += a.x * q2.x + a.y * q2.y + a.z * q2.z + a.w * q2.w;
            acc3 += a.x * q3.x + a.y * q3.y + a.z * q3.z + a.w * q3.w;
        }
        __syncthreads();
    }

    int idx = tid & 63;
    if (ks > 0) {
        red[ks - 1][idx][0] = acc0; red[ks - 1][idx][1] = acc1;
        red[ks - 1][idx][2] = acc2; red[ks - 1][idx][3] = acc3;
    }
    __syncthreads();
    if (ks == 0) {
        #pragma unroll
        for (int r = 0; r < 3; ++r) {
            acc0 += red[r][idx][0]; acc1 += red[r][idx][1];
            acc2 += red[r][idx][2]; acc3 += red[r][idx][3];
        }
        float co = c1c[b * H_ + j];
        float cn = sigm(acc1) * co + sigm(acc0) * tanh_(acc2);
        float hn = sigm(acc3) * tanh_(cn);
        c1n[b * H_ + j] = cn;
        h1n[b * H_ + j] = hn;
    }
}

__global__ __launch_bounds__(256) void k_q(
    const float* __restrict__ w_in, const float* __restrict__ h1n,
    float* __restrict__ q_out)
{
    __shared__ float As[4][32][68];
    __shared__ float red[3][64];

    int tid = threadIdx.x;
    int b  = tid & 31;
    int jl = (tid >> 5) & 1;
    int ks = tid >> 6;
    int j  = blockIdx.x * 2 + jl;

    float acc = 0.0f;
    for (int c = 0; c < 4; ++c) {
        #pragma unroll
        for (int i = 0; i < 8; ++i) {
            int q   = tid + i * 256;
            int ksq = q >> 9;
            int rem = q & 511;
            int bb  = rem >> 4;
            int kq  = rem & 15;
            int kg  = ksq * 256 + c * 64 + kq * 4;
            *(float4*)&As[ksq][bb][kq * 4] = *(const float4*)(h1n + (size_t)bb * H_ + kg);
        }
        __syncthreads();

        int kbase = ks * 256 + c * 64;
        const float4* w0 = (const float4*)(w_in + (size_t)j * H_ + kbase);
        const float4* A4 = (const float4*)&As[ks][b][0];
        #pragma unroll
        for (int kk = 0; kk < 16; ++kk) {
            float4 a  = A4[kk];
            float4 q0 = w0[kk];
            acc += a.x * q0.x + a.y * q0.y + a.z * q0.z + a.w * q0.w;
        }
        __syncthreads();
    }

    int idx = tid & 63;
    if (ks > 0) red[ks - 1][idx] = acc;
    __syncthreads();
    if (ks == 0) {
        acc += red[0][idx] + red[1][idx] + red[2][idx];
        q_out[b * H_ + j] = acc;
    }
}

// ---------------------------------------------------------------------------
// scores[b][s] = x[b] . base[b][s]   grid 512 = b(32) x stile(16), block 256.
// ---------------------------------------------------------------------------
__global__ __launch_bounds__(256) void k_scores(
    const float* __restrict__ x_in, const float* __restrict__ base,
    float* __restrict__ sc_out)
{
    __shared__ float q_lds[1024];

    int b  = blockIdx.x >> 4;
    int st = blockIdx.x & 15;
    int tid  = threadIdx.x;
    int lane = tid & 63;
    int wv   = tid >> 6;

    ((float4*)q_lds)[tid] = ((const float4*)(x_in + (size_t)b * H_))[tid];
    __syncthreads();

    float4 q4[4];
    #pragma unroll
    for (int i = 0; i < 4; ++i) q4[i] = ((const float4*)q_lds)[lane + 64 * i];

    const float* mb = base + (size_t)b * S_ * H_;
    #pragma unroll
    for (int ss = 0; ss < 4; ++ss) {
        int s = st * 16 + wv * 4 + ss;
        const float4* mr = (const float4*)(mb + (size_t)s * H_);
        float a = 0.0f;
        #pragma unroll
        for (int i = 0; i < 4; ++i) {
            float4 m = mr[lane + 64 * i];
            a += q4[i].x * m.x + q4[i].y * m.y + q4[i].z * m.z + q4[i].w * m.w;
        }
        #pragma unroll
        for (int o = 32; o > 0; o >>= 1) a += __shfl_down(a, o);
        if (lane == 0) sc_out[b * S_ + s] = a;
    }
}

// ---------------------------------------------------------------------------
// ctx: local masked softmax of scores + weighted sum.  grid 512, block 256
// ---------------------------------------------------------------------------
__global__ __launch_bounds__(256) void k_ctx(
    const float* __restrict__ sc_in, const float* __restrict__ mem,
    const int* __restrict__ masks,
    float* __restrict__ ctx, float* __restrict__ attn_out, int t)
{
    __shared__ float aw[256];
    __shared__ float red2[4][64];

    int b  = blockIdx.x >> 4;
    int ht = blockIdx.x & 15;
    int tid  = threadIdx.x;
    int lane = tid & 63;
    int wv   = tid >> 6;

    if (wv == 0) {
        int m = 0;
        #pragma unroll
        for (int i = 0; i < 4; ++i) m += masks[b * S_ + lane * 4 + i];
        #pragma unroll
        for (int o = 32; o > 0; o >>= 1) m += __shfl_down(m, o);
        int len = __shfl(m, 0);

        float v[4];
        float mx = -1e30f;
        #pragma unroll
        for (int i = 0; i < 4; ++i) {
            int s = lane + 64 * i;
            float xv = (s < len) ? sc_in[b * S_ + s] : -1e9f;
            v[i] = xv;
            mx = fmaxf(mx, xv);
        }
        #pragma unroll
        for (int o = 32; o > 0; o >>= 1) mx = fmaxf(mx, __shfl_xor(mx, o));
        float sm = 0.0f;
        #pragma unroll
        for (int i = 0; i < 4; ++i) { v[i] = __expf(v[i] - mx); sm += v[i]; }
        #pragma unroll
        for (int o = 32; o > 0; o >>= 1) sm += __shfl_xor(sm, o);
        float inv = 1.0f / sm;
        #pragma unroll
        for (int i = 0; i < 4; ++i) {
            int s = lane + 64 * i;
            float w = v[i] * inv;
            aw[s] = w;
            if (ht == 0) attn_out[((size_t)b * T_ + t) * S_ + s] = w;
        }
    }
    __syncthreads();

    int h = ht * 64 + lane;
    const float* mb = mem + (size_t)b * S_ * H_;
    float a = 0.0f;
    #pragma unroll 8
    for (int ss = 0; ss < 64; ++ss) {
        int s = wv * 64 + ss;
        a += aw[s] * mb[(size_t)s * H_ + h];
    }
    red2[wv][lane] = a;
    __syncthreads();
    if (tid < 64) {
        float r = red2[0][tid] + red2[1][tid] + red2[2][tid] + red2[3][tid];
        ctx[b * H_ + ht * 64 + tid] = r;
    }
}

// -------- out = tanh([ctx | h1n] @ w_out^T) --------------------------------
__global__ __launch_bounds__(256) void k_out(
    const float* __restrict__ w_out, const float* __restrict__ ctx,
    const float* __restrict__ h1n,
    float* __restrict__ feedn, float* __restrict__ dout, int t)
{
    __shared__ float As[4][32][68];
    __shared__ float red[3][64];

    int tid = threadIdx.x;
    int b  = tid & 31;
    int jl = (tid >> 5) & 1;
    int ks = tid >> 6;
    int j  = blockIdx.x * 2 + jl;

    float acc = 0.0f;
    for (int c = 0; c < 8; ++c) {
        #pragma unroll
        for (int i = 0; i < 8; ++i) {
            int q   = tid + i * 256;
            int ksq = q >> 9;
            int rem = q & 511;
            int bb  = rem >> 4;
            int kq  = rem & 15;
            int kg  = ksq * 512 + c * 64 + kq * 4;
            const float* src = (kg < 1024) ? (ctx + (size_t)bb * H_ + kg)
                                           : (h1n + (size_t)bb * H_ + (kg - 1024));
            *(float4*)&As[ksq][bb][kq * 4] = *(const float4*)src;
        }
        __syncthreads();

        int kbase = ks * 512 + c * 64;
        const float4* w0 = (const float4*)(w_out + (size_t)j * 2048 + kbase);
        const float4* A4 = (const float4*)&As[ks][b][0];
        #pragma unroll
        for (int kk = 0; kk < 16; ++kk) {
            float4 a  = A4[kk];
            float4 q0 = w0[kk];
            acc += a.x * q0.x + a.y * q0.y + a.z * q0.z + a.w * q0.w;
        }
        __syncthreads();
    }

    int idx = tid & 63;
    if (ks > 0) red[ks - 1][idx] = acc;
    __syncthreads();
    if (ks == 0) {
        acc += red[0][idx] + red[1][idx] + red[2][idx];
        float o = tanh_(acc);
        feedn[b * H_ + j] = o;
        dout[((size_t)b * T_ + t) * H_ + j] = o;
    }
}

// ---------------------------------------------------------------------------
extern "C" void kernel_launch(void* const* d_in, const int* in_sizes, int n_in,
                              void* d_out, int out_size, void* d_ws, size_t ws_size,
                              hipStream_t stream) {
    const int*   tgt    = (const int*)  d_in[0];
    const float* mem    = (const float*)d_in[1];
    const int*   masks  = (const int*)  d_in[2];
    const float* h0in   = (const float*)d_in[3];
    const float* c0in   = (const float*)d_in[4];
    const float* emb    = (const float*)d_in[5];
    const float* w_ih0  = (const float*)d_in[6];
    const float* w_hh0  = (const float*)d_in[7];
    const float* b_ih0  = (const float*)d_in[8];
    const float* b_hh0  = (const float*)d_in[9];
    const float* w_ih1  = (const float*)d_in[10];
    const float* w_hh1  = (const float*)d_in[11];
    const float* b_ih1  = (const float*)d_in[12];
    const float* b_hh1  = (const float*)d_in[13];
    const float* w_in   = (const float*)d_in[14];
    const float* w_out  = (const float*)d_in[15];

    float* dout     = (float*)d_out;
    float* attn_out = dout + (size_t)B_ * T_ * H_;

    float* ws   = (float*)d_ws;
    float* h0s  = ws;              // [2][B*H]
    float* c0s  = h0s  + 2 * BH_;  // [2][B*H]
    float* h1s  = c0s  + 2 * BH_;  // [2][B*H]
    float* c1s  = h1s  + 2 * BH_;  // [2][B*H]
    float* feed = c1s  + 2 * BH_;  // [2][B*H]
    float* qctx = feed + 2 * BH_;  // [B*H]
    float* scw  = qctx + BH_;      // [B*S]
    float* pmem = scw  + B_ * S_;  // [B*S*H]      33.5 MB
    float* gemb = pmem + (size_t)B_ * S_ * H_;     // [B*T*4096]  33.5 MB
    float* part0 = gemb + (size_t)B_ * T_ * 4096;  // [8][32][4096]  4 MB
    float* part1 = part0 + (size_t)8 * 32 * 4096;  // [8][32][4096]  4 MB

    const size_t base_fl = (size_t)11 * BH_ + B_ * S_;
    const size_t big_fl  = (size_t)B_ * S_ * H_ + (size_t)B_ * T_ * 4096;
    const size_t needA = (base_fl + big_fl + (size_t)2 * 8 * 32 * 4096) * 4;
    const size_t needB = (base_fl + big_fl) * 4;

    k_init<<<128, 256, 0, stream>>>(h0in, c0in, h0s, c0s, h1s, c1s, feed);

    if (ws_size >= needA) {
        // ---------- tier A: tiled k-split gate GEMMs + cell kernels ----------
        k_pmem<<<dim3(128, 16), 256, 0, stream>>>(mem, w_in, pmem);
        k_gemb<<<dim3(32, 64), 256, 0, stream>>>(tgt, emb, w_ih0, gemb);

        for (int t = 0; t < T_; ++t) {
            int cur = t & 1, nxt = cur ^ 1;
            k_gates<<<dim3(64, 8), 256, 0, stream>>>(
                feed + cur * BH_, h0s + cur * BH_,
                w_ih0 + 512, 1536, w_hh0, 1024, part0);
            k_cell<<<128, 256, 0, stream>>>(part0, b_ih0, b_hh0, gemb, 1,
                                            c0s + cur * BH_, c0s + nxt * BH_,
                                            h0s + nxt * BH_, t);
            k_gates<<<dim3(64, 8), 256, 0, stream>>>(
                h0s + nxt * BH_, h1s + cur * BH_,
                w_ih1, 1024, w_hh1, 1024, part1);
            k_cell<<<128, 256, 0, stream>>>(part1, b_ih1, b_hh1, gemb, 0,
                                            c1s + cur * BH_, c1s + nxt * BH_,
                                            h1s + nxt * BH_, t);
            k_scores<<<512, 256, 0, stream>>>(h1s + nxt * BH_, pmem, scw);
            k_ctx<<<512, 256, 0, stream>>>(scw, mem, masks, qctx, attn_out, t);
            k_out<<<512, 256, 0, stream>>>(w_out, qctx, h1s + nxt * BH_,
                                           feed + nxt * BH_, dout, t);
        }
    } else if (ws_size >= needB) {
        // ---------- tier B: R13 champion (7.69 ms) ----------
        k_pmem<<<dim3(128, 16), 256, 0, stream>>>(mem, w_in, pmem);
        k_gemb<<<dim3(32, 64), 256, 0, stream>>>(tgt, emb, w_ih0, gemb);

        for (int t = 0; t < T_; ++t) {
            int cur = t & 1, nxt = cur ^ 1;
            k_lstm0g<<<512, 256, 0, stream>>>(gemb, w_ih0, w_hh0, b_ih0, b_hh0,
                                              feed + cur * BH_, h0s + cur * BH_, c0s + cur * BH_,
                                              h0s + nxt * BH_, c0s + nxt * BH_, t);
            k_lstm1<<<512, 256, 0, stream>>>(w_ih1, w_hh1, b_ih1, b_hh1,
                                             h0s + nxt * BH_, h1s + cur * BH_, c1s + cur * BH_,
                                             h1s + nxt * BH_, c1s + nxt * BH_);
            k_scores<<<512, 256, 0, stream>>>(h1s + nxt * BH_, pmem, scw);
            k_ctx<<<512, 256, 0, stream>>>(scw, mem, masks, qctx, attn_out, t);
            k_out<<<512, 256, 0, stream>>>(w_out, qctx, h1s + nxt * BH_,
                                           feed + nxt * BH_, dout, t);
        }
    } else {
        // ---------- minimal tier (round-2) ----------
        for (int t = 0; t < T_; ++t) {
            int cur = t & 1, nxt = cur ^ 1;
            k_lstm0<<<512, 256, 0, stream>>>(tgt, emb, w_ih0, w_hh0, b_ih0, b_hh0,
                                             feed + cur * BH_, h0s + cur * BH_, c0s + cur * BH_,
                                             h0s + nxt * BH_, c0s + nxt * BH_, t);
            k_lstm1<<<512, 256, 0, stream>>>(w_ih1, w_hh1, b_ih1, b_hh1,
                                             h0s + nxt * BH_, h1s + cur * BH_, c1s + cur * BH_,
                                             h1s + nxt * BH_, c1s + nxt * BH_);
            k_q<<<512, 256, 0, stream>>>(w_in, h1s + nxt * BH_, qctx);
            k_scores<<<512, 256, 0, stream>>>(qctx, mem, scw);
            k_ctx<<<512, 256, 0, stream>>>(scw, mem, masks, qctx, attn_out, t);
            k_out<<<512, 256, 0, stream>>>(w_out, qctx, h1s + nxt * BH_,
                                           feed + nxt * BH_, dout, t);
        }
    }
}

// Round 15
// 5115.550 us; speedup vs baseline: 1.7244x; 1.1402x over previous
//
#include <hip/hip_runtime.h>
#include <math.h>

#define B_ 32
#define T_ 64
#define S_ 256
#define H_ 1024
#define E_ 512
#define BH_ (B_ * H_)

__device__ __forceinline__ float sigm(float x) {
    return 1.0f / (1.0f + __expf(-x));
}
__device__ __forceinline__ float tanh_(float x) {
    x = fminf(15.0f, fmaxf(-15.0f, x));
    float e = __expf(-2.0f * x);
    return (1.0f - e) / (1.0f + e);
}

// ---------------------------------------------------------------------------
// init: state ping-pong slot 0 + zero input feed
// ---------------------------------------------------------------------------
__global__ void k_init(const float* __restrict__ h0in, const float* __restrict__ c0in,
                       float* h0s, float* c0s, float* h1s, float* c1s, float* feed) {
    int i = blockIdx.x * 256 + threadIdx.x;
    if (i < BH_) {
        h0s[i]  = h0in[i];
        h1s[i]  = h0in[BH_ + i];
        c0s[i]  = c0in[i];
        c1s[i]  = c0in[BH_ + i];
        feed[i] = 0.0f;
    }
}

// ---------------------------------------------------------------------------
// pmem[r][k] = sum_j mem[r][j] * w_in[j][k]   (time-invariant; R7-proven)
// ---------------------------------------------------------------------------
__global__ __launch_bounds__(256) void k_pmem(
    const float* __restrict__ mem, const float* __restrict__ w_in,
    float* __restrict__ pmem)
{
    __shared__ float As[64][36];
    __shared__ float Bs[32][68];

    const int tid = threadIdx.x;
    const int rt = blockIdx.x * 64;
    const int ct = blockIdx.y * 64;
    const int tx = tid & 15;
    const int ty = tid >> 4;

    float acc[4][4] = {{0.f}};

    for (int jc = 0; jc < 1024; jc += 32) {
        #pragma unroll
        for (int i = 0; i < 2; ++i) {
            int s2  = tid + i * 256;
            int row = s2 >> 3, kq = s2 & 7;
            *(float4*)&As[row][kq * 4] =
                *(const float4*)(mem + (size_t)(rt + row) * 1024 + jc + kq * 4);
        }
        #pragma unroll
        for (int i = 0; i < 2; ++i) {
            int s2 = tid + i * 256;
            int kk = s2 >> 4, cq = s2 & 15;
            *(float4*)&Bs[kk][cq * 4] =
                *(const float4*)(w_in + (size_t)(jc + kk) * 1024 + ct + cq * 4);
        }
        __syncthreads();

        #pragma unroll
        for (int kk = 0; kk < 32; ++kk) {
            float a0 = As[ty * 4 + 0][kk], a1 = As[ty * 4 + 1][kk];
            float a2 = As[ty * 4 + 2][kk], a3 = As[ty * 4 + 3][kk];
            float b0 = Bs[kk][tx * 4 + 0], b1 = Bs[kk][tx * 4 + 1];
            float b2 = Bs[kk][tx * 4 + 2], b3 = Bs[kk][tx * 4 + 3];
            acc[0][0] += a0 * b0; acc[0][1] += a0 * b1; acc[0][2] += a0 * b2; acc[0][3] += a0 * b3;
            acc[1][0] += a1 * b0; acc[1][1] += a1 * b1; acc[1][2] += a1 * b2; acc[1][3] += a1 * b3;
            acc[2][0] += a2 * b0; acc[2][1] += a2 * b1; acc[2][2] += a2 * b2; acc[2][3] += a2 * b3;
            acc[3][0] += a3 * b0; acc[3][1] += a3 * b1; acc[3][2] += a3 * b2; acc[3][3] += a3 * b3;
        }
        __syncthreads();
    }

    #pragma unroll
    for (int i = 0; i < 4; ++i) {
        float4 v = make_float4(acc[i][0], acc[i][1], acc[i][2], acc[i][3]);
        *(float4*)(pmem + (size_t)(rt + ty * 4 + i) * 1024 + ct + tx * 4) = v;
    }
}

// ---------------------------------------------------------------------------
// gemb[r][n] = sum_k emb[tgt[r]][k] * w_ih0[n][k]   (r = b*64+t; K = 512)
// ---------------------------------------------------------------------------
__global__ __launch_bounds__(256) void k_gemb(
    const int* __restrict__ tgt, const float* __restrict__ emb,
    const float* __restrict__ w_ih0, float* __restrict__ gemb)
{
    __shared__ float As[64][36];
    __shared__ float Bs[64][37];
    __shared__ int   tok_s[64];

    const int tid = threadIdx.x;
    const int rt = blockIdx.x * 64;
    const int ct = blockIdx.y * 64;
    const int tx = tid & 15;
    const int ty = tid >> 4;

    if (tid < 64) tok_s[tid] = tgt[rt + tid];
    __syncthreads();

    float acc[4][4] = {{0.f}};

    for (int jc = 0; jc < 512; jc += 32) {
        #pragma unroll
        for (int i = 0; i < 2; ++i) {
            int s2  = tid + i * 256;
            int row = s2 >> 3, kq = s2 & 7;
            *(float4*)&As[row][kq * 4] =
                *(const float4*)(emb + (size_t)tok_s[row] * E_ + jc + kq * 4);
        }
        #pragma unroll
        for (int i = 0; i < 2; ++i) {
            int s2 = tid + i * 256;
            int n  = s2 >> 3, kq = s2 & 7;
            *(float4*)&Bs[n][kq * 4] =
                *(const float4*)(w_ih0 + (size_t)(ct + n) * 1536 + jc + kq * 4);
        }
        __syncthreads();

        #pragma unroll
        for (int kk = 0; kk < 32; ++kk) {
            float a0 = As[ty * 4 + 0][kk], a1 = As[ty * 4 + 1][kk];
            float a2 = As[ty * 4 + 2][kk], a3 = As[ty * 4 + 3][kk];
            float b0 = Bs[tx * 4 + 0][kk], b1 = Bs[tx * 4 + 1][kk];
            float b2 = Bs[tx * 4 + 2][kk], b3 = Bs[tx * 4 + 3][kk];
            acc[0][0] += a0 * b0; acc[0][1] += a0 * b1; acc[0][2] += a0 * b2; acc[0][3] += a0 * b3;
            acc[1][0] += a1 * b0; acc[1][1] += a1 * b1; acc[1][2] += a1 * b2; acc[1][3] += a1 * b3;
            acc[2][0] += a2 * b0; acc[2][1] += a2 * b1; acc[2][2] += a2 * b2; acc[2][3] += a2 * b3;
            acc[3][0] += a3 * b0; acc[3][1] += a3 * b1; acc[3][2] += a3 * b2; acc[3][3] += a3 * b3;
        }
        __syncthreads();
    }

    #pragma unroll
    for (int i = 0; i < 4; ++i) {
        float4 v = make_float4(acc[i][0], acc[i][1], acc[i][2], acc[i][3]);
        *(float4*)(gemb + (size_t)(rt + ty * 4 + i) * 4096 + ct + tx * 4) = v;
    }
}

// ---------------------------------------------------------------------------
// k_gates: part[ks][b][nstride] = sum_{k in slice} A[b][k] * W[n][k]
// A = [a0 (k<1024) | a1 (k>=1024)]; W row n: wa (k<1024) / wb.  K-slice =
// kslice (multiple of 32, divides 1024).  grid (nstride/64, 2048/kslice),
// block 256 = 16tx x 16ty, 32b x 64n tile, per-thread 2b x 4n.  R14-proven.
// ---------------------------------------------------------------------------
__global__ __launch_bounds__(256) void k_gates(
    const float* __restrict__ a0, const float* __restrict__ a1,
    const float* __restrict__ wa, int lda,
    const float* __restrict__ wb, int ldb,
    float* __restrict__ part, int nstride, int kslice)
{
    __shared__ float As[32][33];
    __shared__ float Bs[64][33];

    const int tid = threadIdx.x;
    const int nt = blockIdx.x;
    const int ks = blockIdx.y;
    const int tx = tid & 15;
    const int ty = tid >> 4;

    const int k0 = ks * kslice;
    const bool hi = (k0 >= 1024);
    const float* a   = hi ? a1 : a0;
    const float* w   = hi ? wb : wa;
    const int    ldw = hi ? ldb : lda;
    const int    ko  = hi ? (k0 - 1024) : k0;
    const int    nchunks = kslice >> 5;

    float acc[2][4] = {{0.f, 0.f, 0.f, 0.f}, {0.f, 0.f, 0.f, 0.f}};

    for (int c = 0; c < nchunks; ++c) {
        {   // A: 32 b x 32 k, 1 float4/thread
            int row = tid >> 3, kq = tid & 7;
            float4 v = *(const float4*)(a + (size_t)row * H_ + ko + c * 32 + kq * 4);
            As[row][kq * 4 + 0] = v.x; As[row][kq * 4 + 1] = v.y;
            As[row][kq * 4 + 2] = v.z; As[row][kq * 4 + 3] = v.w;
        }
        #pragma unroll
        for (int i = 0; i < 2; ++i) {   // W: 64 n x 32 k
            int s2 = tid + i * 256;
            int n = s2 >> 3, kq = s2 & 7;
            float4 v = *(const float4*)(w + (size_t)(nt * 64 + n) * ldw + ko + c * 32 + kq * 4);
            Bs[n][kq * 4 + 0] = v.x; Bs[n][kq * 4 + 1] = v.y;
            Bs[n][kq * 4 + 2] = v.z; Bs[n][kq * 4 + 3] = v.w;
        }
        __syncthreads();

        #pragma unroll
        for (int kk = 0; kk < 32; ++kk) {
            float av0 = As[ty * 2 + 0][kk];
            float av1 = As[ty * 2 + 1][kk];
            float b0 = Bs[tx * 4 + 0][kk], b1 = Bs[tx * 4 + 1][kk];
            float b2 = Bs[tx * 4 + 2][kk], b3 = Bs[tx * 4 + 3][kk];
            acc[0][0] += av0 * b0; acc[0][1] += av0 * b1;
            acc[0][2] += av0 * b2; acc[0][3] += av0 * b3;
            acc[1][0] += av1 * b0; acc[1][1] += av1 * b1;
            acc[1][2] += av1 * b2; acc[1][3] += av1 * b3;
        }
        __syncthreads();
    }

    #pragma unroll
    for (int r = 0; r < 2; ++r) {
        int b = ty * 2 + r;
        float4 v = make_float4(acc[r][0], acc[r][1], acc[r][2], acc[r][3]);
        *(float4*)(part + ((size_t)ks * 32 + b) * nstride + nt * 64 + tx * 4) = v;
    }
}

// ---------------------------------------------------------------------------
// k_cell: sum 8 k-split partials + biases (+ gemb for layer 0), apply LSTM
// cell.  grid 128, block 256.
// ---------------------------------------------------------------------------
__global__ __launch_bounds__(256) void k_cell(
    const float* __restrict__ part,
    const float* __restrict__ b_ih, const float* __restrict__ b_hh,
    const float* __restrict__ ge, int has_ge,
    const float* __restrict__ c_cur, float* __restrict__ c_nxt,
    float* __restrict__ h_nxt, int t)
{
    int idx = blockIdx.x * 256 + threadIdx.x;
    int b = idx >> 10;
    int j = idx & 1023;

    float g0 = b_ih[0 * H_ + j] + b_hh[0 * H_ + j];
    float g1 = b_ih[1 * H_ + j] + b_hh[1 * H_ + j];
    float g2 = b_ih[2 * H_ + j] + b_hh[2 * H_ + j];
    float g3 = b_ih[3 * H_ + j] + b_hh[3 * H_ + j];
    if (has_ge) {
        const float* g = ge + ((size_t)b * 64 + t) * 4096;
        g0 += g[0 * H_ + j]; g1 += g[1 * H_ + j];
        g2 += g[2 * H_ + j]; g3 += g[3 * H_ + j];
    }
    #pragma unroll
    for (int p = 0; p < 8; ++p) {
        const float* pp = part + ((size_t)p * 32 + b) * 4096;
        g0 += pp[0 * H_ + j]; g1 += pp[1 * H_ + j];
        g2 += pp[2 * H_ + j]; g3 += pp[3 * H_ + j];
    }
    float co = c_cur[b * H_ + j];
    float cn = sigm(g1) * co + sigm(g0) * tanh_(g2);
    c_nxt[b * H_ + j] = cn;
    h_nxt[b * H_ + j] = sigm(g3) * tanh_(cn);
}

// ---------------------------------------------------------------------------
// k_outcell: sum 16 k-split partials, tanh, write feed_next + dout[:, t]
// grid 128, block 256.
// ---------------------------------------------------------------------------
__global__ __launch_bounds__(256) void k_outcell(
    const float* __restrict__ part,
    float* __restrict__ feedn, float* __restrict__ dout, int t)
{
    int idx = blockIdx.x * 256 + threadIdx.x;
    int b = idx >> 10;
    int j = idx & 1023;

    float g = 0.0f;
    #pragma unroll
    for (int p = 0; p < 16; ++p)
        g += part[((size_t)p * 32 + b) * 1024 + j];

    float o = tanh_(g);
    feedn[b * H_ + j] = o;
    dout[((size_t)b * T_ + t) * H_ + j] = o;
}

// ---------------------------------------------------------------------------
// scores[b][s] = x[b] . base[b][s]   grid 512 = b(32) x stile(16), block 256.
// ---------------------------------------------------------------------------
__global__ __launch_bounds__(256) void k_scores(
    const float* __restrict__ x_in, const float* __restrict__ base,
    float* __restrict__ sc_out)
{
    __shared__ float q_lds[1024];

    int b  = blockIdx.x >> 4;
    int st = blockIdx.x & 15;
    int tid  = threadIdx.x;
    int lane = tid & 63;
    int wv   = tid >> 6;

    ((float4*)q_lds)[tid] = ((const float4*)(x_in + (size_t)b * H_))[tid];
    __syncthreads();

    float4 q4[4];
    #pragma unroll
    for (int i = 0; i < 4; ++i) q4[i] = ((const float4*)q_lds)[lane + 64 * i];

    const float* mb = base + (size_t)b * S_ * H_;
    #pragma unroll
    for (int ss = 0; ss < 4; ++ss) {
        int s = st * 16 + wv * 4 + ss;
        const float4* mr = (const float4*)(mb + (size_t)s * H_);
        float a = 0.0f;
        #pragma unroll
        for (int i = 0; i < 4; ++i) {
            float4 m = mr[lane + 64 * i];
            a += q4[i].x * m.x + q4[i].y * m.y + q4[i].z * m.z + q4[i].w * m.w;
        }
        #pragma unroll
        for (int o = 32; o > 0; o >>= 1) a += __shfl_down(a, o);
        if (lane == 0) sc_out[b * S_ + s] = a;
    }
}

// ---------------------------------------------------------------------------
// ctx: local masked softmax of scores + weighted sum.  grid 512, block 256
// ---------------------------------------------------------------------------
__global__ __launch_bounds__(256) void k_ctx(
    const float* __restrict__ sc_in, const float* __restrict__ mem,
    const int* __restrict__ masks,
    float* __restrict__ ctx, float* __restrict__ attn_out, int t)
{
    __shared__ float aw[256];
    __shared__ float red2[4][64];

    int b  = blockIdx.x >> 4;
    int ht = blockIdx.x & 15;
    int tid  = threadIdx.x;
    int lane = tid & 63;
    int wv   = tid >> 6;

    if (wv == 0) {
        int m = 0;
        #pragma unroll
        for (int i = 0; i < 4; ++i) m += masks[b * S_ + lane * 4 + i];
        #pragma unroll
        for (int o = 32; o > 0; o >>= 1) m += __shfl_down(m, o);
        int len = __shfl(m, 0);

        float v[4];
        float mx = -1e30f;
        #pragma unroll
        for (int i = 0; i < 4; ++i) {
            int s = lane + 64 * i;
            float xv = (s < len) ? sc_in[b * S_ + s] : -1e9f;
            v[i] = xv;
            mx = fmaxf(mx, xv);
        }
        #pragma unroll
        for (int o = 32; o > 0; o >>= 1) mx = fmaxf(mx, __shfl_xor(mx, o));
        float sm = 0.0f;
        #pragma unroll
        for (int i = 0; i < 4; ++i) { v[i] = __expf(v[i] - mx); sm += v[i]; }
        #pragma unroll
        for (int o = 32; o > 0; o >>= 1) sm += __shfl_xor(sm, o);
        float inv = 1.0f / sm;
        #pragma unroll
        for (int i = 0; i < 4; ++i) {
            int s = lane + 64 * i;
            float w = v[i] * inv;
            aw[s] = w;
            if (ht == 0) attn_out[((size_t)b * T_ + t) * S_ + s] = w;
        }
    }
    __syncthreads();

    int h = ht * 64 + lane;
    const float* mb = mem + (size_t)b * S_ * H_;
    float a = 0.0f;
    #pragma unroll 8
    for (int ss = 0; ss < 64; ++ss) {
        int s = wv * 64 + ss;
        a += aw[s] * mb[(size_t)s * H_ + h];
    }
    red2[wv][lane] = a;
    __syncthreads();
    if (tid < 64) {
        float r = red2[0][tid] + red2[1][tid] + red2[2][tid] + red2[3][tid];
        ctx[b * H_ + ht * 64 + tid] = r;
    }
}

// ===========================================================================
// Fallback kernels (R13 champion tier + minimal tier)
// ===========================================================================
__global__ __launch_bounds__(256) void k_lstm0(
    const int* __restrict__ tgt, const float* __restrict__ emb,
    const float* __restrict__ w_ih0, const float* __restrict__ w_hh0,
    const float* __restrict__ b_ih0, const float* __restrict__ b_hh0,
    const float* __restrict__ feed, const float* __restrict__ h0c,
    const float* __restrict__ c0c,
    float* __restrict__ h0n, float* __restrict__ c0n, int t)
{
    __shared__ float As[4][32][68];
    __shared__ float red[3][64][4];
    __shared__ int   tok[32];

    int tid = threadIdx.x;
    int b  = tid & 31;
    int jl = (tid >> 5) & 1;
    int ks = tid >> 6;
    int j  = blockIdx.x * 2 + jl;

    if (tid < 32) tok[tid] = tgt[tid * T_ + t];
    __syncthreads();

    float acc0, acc1, acc2, acc3;
    if (ks == 0) {
        acc0 = b_ih0[0 * H_ + j] + b_hh0[0 * H_ + j];
        acc1 = b_ih0[1 * H_ + j] + b_hh0[1 * H_ + j];
        acc2 = b_ih0[2 * H_ + j] + b_hh0[2 * H_ + j];
        acc3 = b_ih0[3 * H_ + j] + b_hh0[3 * H_ + j];
    } else {
        acc0 = acc1 = acc2 = acc3 = 0.0f;
    }

    for (int c = 0; c < 10; ++c) {
        #pragma unroll
        for (int i = 0; i < 8; ++i) {
            int q   = tid + i * 256;
            int ksq = q >> 9;
            int rem = q & 511;
            int bb  = rem >> 4;
            int kq  = rem & 15;
            int kg  = ksq * 640 + c * 64 + kq * 4;
            const float* src;
            if (kg < 512)        src = emb  + (size_t)tok[bb] * E_ + kg;
            else if (kg < 1536)  src = feed + (size_t)bb * H_ + (kg - 512);
            else                 src = h0c  + (size_t)bb * H_ + (kg - 1536);
            *(float4*)&As[ksq][bb][kq * 4] = *(const float4*)src;
        }
        __syncthreads();

        int kbase = ks * 640 + c * 64;
        const float4 *w0, *w1, *w2, *w3;
        if (kbase < 1536) {
            w0 = (const float4*)(w_ih0 + (size_t)(0 * H_ + j) * 1536 + kbase);
            w1 = (const float4*)(w_ih0 + (size_t)(1 * H_ + j) * 1536 + kbase);
            w2 = (const float4*)(w_ih0 + (size_t)(2 * H_ + j) * 1536 + kbase);
            w3 = (const float4*)(w_ih0 + (size_t)(3 * H_ + j) * 1536 + kbase);
        } else {
            int kb = kbase - 1536;
            w0 = (const float4*)(w_hh0 + (size_t)(0 * H_ + j) * 1024 + kb);
            w1 = (const float4*)(w_hh0 + (size_t)(1 * H_ + j) * 1024 + kb);
            w2 = (const float4*)(w_hh0 + (size_t)(2 * H_ + j) * 1024 + kb);
            w3 = (const float4*)(w_hh0 + (size_t)(3 * H_ + j) * 1024 + kb);
        }
        const float4* A4 = (const float4*)&As[ks][b][0];
        #pragma unroll
        for (int kk = 0; kk < 16; ++kk) {
            float4 a  = A4[kk];
            float4 q0 = w0[kk], q1 = w1[kk], q2 = w2[kk], q3 = w3[kk];
            acc0 += a.x * q0.x + a.y * q0.y + a.z * q0.z + a.w * q0.w;
            acc1 += a.x * q1.x + a.y * q1.y + a.z * q1.z + a.w * q1.w;
            acc2 += a.x * q2.x + a.y * q2.y + a.z * q2.z + a.w * q2.w;
            acc3 += a.x * q3.x + a.y * q3.y + a.z * q3.z + a.w * q3.w;
        }
        __syncthreads();
    }

    int idx = tid & 63;
    if (ks > 0) {
        red[ks - 1][idx][0] = acc0; red[ks - 1][idx][1] = acc1;
        red[ks - 1][idx][2] = acc2; red[ks - 1][idx][3] = acc3;
    }
    __syncthreads();
    if (ks == 0) {
        #pragma unroll
        for (int r = 0; r < 3; ++r) {
            acc0 += red[r][idx][0]; acc1 += red[r][idx][1];
            acc2 += red[r][idx][2]; acc3 += red[r][idx][3];
        }
        float co = c0c[b * H_ + j];
        float cn = sigm(acc1) * co + sigm(acc0) * tanh_(acc2);
        float hn = sigm(acc3) * tanh_(cn);
        c0n[b * H_ + j] = cn;
        h0n[b * H_ + j] = hn;
    }
}

__global__ __launch_bounds__(256) void k_lstm1(
    const float* __restrict__ w_ih1, const float* __restrict__ w_hh1,
    const float* __restrict__ b_ih1, const float* __restrict__ b_hh1,
    const float* __restrict__ x, const float* __restrict__ h1c,
    const float* __restrict__ c1c,
    float* __restrict__ h1n, float* __restrict__ c1n)
{
    __shared__ float As[4][32][68];
    __shared__ float red[3][64][4];

    int tid = threadIdx.x;
    int b  = tid & 31;
    int jl = (tid >> 5) & 1;
    int ks = tid >> 6;
    int j  = blockIdx.x * 2 + jl;

    float acc0, acc1, acc2, acc3;
    if (ks == 0) {
        acc0 = b_ih1[0 * H_ + j] + b_hh1[0 * H_ + j];
        acc1 = b_ih1[1 * H_ + j] + b_hh1[1 * H_ + j];
        acc2 = b_ih1[2 * H_ + j] + b_hh1[2 * H_ + j];
        acc3 = b_ih1[3 * H_ + j] + b_hh1[3 * H_ + j];
    } else {
        acc0 = acc1 = acc2 = acc3 = 0.0f;
    }

    for (int c = 0; c < 8; ++c) {
        #pragma unroll
        for (int i = 0; i < 8; ++i) {
            int q   = tid + i * 256;
            int ksq = q >> 9;
            int rem = q & 511;
            int bb  = rem >> 4;
            int kq  = rem & 15;
            int kg  = ksq * 512 + c * 64 + kq * 4;
            const float* src = (kg < 1024) ? (x + (size_t)bb * H_ + kg)
                                           : (h1c + (size_t)bb * H_ + (kg - 1024));
            *(float4*)&As[ksq][bb][kq * 4] = *(const float4*)src;
        }
        __syncthreads();

        int kbase = ks * 512 + c * 64;
        const float* wb;
        int ko;
        if (kbase < 1024) { wb = w_ih1; ko = kbase; }
        else              { wb = w_hh1; ko = kbase - 1024; }
        const float4* w0 = (const float4*)(wb + (size_t)(0 * H_ + j) * H_ + ko);
        const float4* w1 = (const float4*)(wb + (size_t)(1 * H_ + j) * H_ + ko);
        const float4* w2 = (const float4*)(wb + (size_t)(2 * H_ + j) * H_ + ko);
        const float4* w3 = (const float4*)(wb + (size_t)(3 * H_ + j) * H_ + ko);
        const float4* A4 = (const float4*)&As[ks][b][0];
        #pragma unroll
        for (int kk = 0; kk < 16; ++kk) {
            float4 a  = A4[kk];
            float4 q0 = w0[kk], q1 = w1[kk], q2 = w2[kk], q3 = w3[kk];
            acc0 += a.x * q0.x + a.y * q0.y + a.z * q0.z + a.w * q0.w;
            acc1 += a.x * q1.x + a.y * q1.y + a.z * q1.z + a.w * q1.w;
            acc2 += a.x * q2.x + a.y * q2.y + a.z * q2.z + a.w * q2.w;
            acc3 += a.x * q3.x + a.y * q3.y + a.z * q3.z + a.w * q3.w;
        }
        __syncthreads();
    }

    int idx = tid & 63;
    if (ks > 0) {
        red[ks - 1][idx][0] = acc0; red[ks - 1][idx][1] = acc1;
        red[ks - 1][idx][2] = acc2; red[ks - 1][idx][3] = acc3;
    }
    __syncthreads();
    if (ks == 0) {
        #pragma unroll
        for (int r = 0; r < 3; ++r) {
            acc0 += red[r][idx][0]; acc1 += red[r][idx][1];
            acc2 += red[r][idx][2]; acc3 += red[r][idx][3];
        }
        float co = c1c[b * H_ + j];
        float cn = sigm(acc1) * co + sigm(acc0) * tanh_(acc2);
        float hn = sigm(acc3) * tanh_(cn);
        c1n[b * H_ + j] = cn;
        h1n[b * H_ + j] = hn;
    }
}

__global__ __launch_bounds__(256) void k_q(
    const float* __restrict__ w_in, const float* __restrict__ h1n,
    float* __restrict__ q_out)
{
    __shared__ float As[4][32][68];
    __shared__ float red[3][64];

    int tid = threadIdx.x;
    int b  = tid & 31;
    int jl = (tid >> 5) & 1;
    int ks = tid >> 6;
    int j  = blockIdx.x * 2 + jl;

    float acc = 0.0f;
    for (int c = 0; c < 4; ++c) {
        #pragma unroll
        for (int i = 0; i < 8; ++i) {
            int q   = tid + i * 256;
            int ksq = q >> 9;
            int rem = q & 511;
            int bb  = rem >> 4;
            int kq  = rem & 15;
            int kg  = ksq * 256 + c * 64 + kq * 4;
            *(float4*)&As[ksq][bb][kq * 4] = *(const float4*)(h1n + (size_t)bb * H_ + kg);
        }
        __syncthreads();

        int kbase = ks * 256 + c * 64;
        const float4* w0 = (const float4*)(w_in + (size_t)j * H_ + kbase);
        const float4* A4 = (const float4*)&As[ks][b][0];
        #pragma unroll
        for (int kk = 0; kk < 16; ++kk) {
            float4 a  = A4[kk];
            float4 q0 = w0[kk];
            acc += a.x * q0.x + a.y * q0.y + a.z * q0.z + a.w * q0.w;
        }
        __syncthreads();
    }

    int idx = tid & 63;
    if (ks > 0) red[ks - 1][idx] = acc;
    __syncthreads();
    if (ks == 0) {
        acc += red[0][idx] + red[1][idx] + red[2][idx];
        q_out[b * H_ + j] = acc;
    }
}

__global__ __launch_bounds__(256) void k_out(
    const float* __restrict__ w_out, const float* __restrict__ ctx,
    const float* __restrict__ h1n,
    float* __restrict__ feedn, float* __restrict__ dout, int t)
{
    __shared__ float As[4][32][68];
    __shared__ float red[3][64];

    int tid = threadIdx.x;
    int b  = tid & 31;
    int jl = (tid >> 5) & 1;
    int ks = tid >> 6;
    int j  = blockIdx.x * 2 + jl;

    float acc = 0.0f;
    for (int c = 0; c < 8; ++c) {
        #pragma unroll
        for (int i = 0; i < 8; ++i) {
            int q   = tid + i * 256;
            int ksq = q >> 9;
            int rem = q & 511;
            int bb  = rem >> 4;
            int kq  = rem & 15;
            int kg  = ksq * 512 + c * 64 + kq * 4;
            const float* src = (kg < 1024) ? (ctx + (size_t)bb * H_ + kg)
                                           : (h1n + (size_t)bb * H_ + (kg - 1024));
            *(float4*)&As[ksq][bb][kq * 4] = *(const float4*)src;
        }
        __syncthreads();

        int kbase = ks * 512 + c * 64;
        const float4* w0 = (const float4*)(w_out + (size_t)j * 2048 + kbase);
        const float4* A4 = (const float4*)&As[ks][b][0];
        #pragma unroll
        for (int kk = 0; kk < 16; ++kk) {
            float4 a  = A4[kk];
            float4 q0 = w0[kk];
            acc += a.x * q0.x + a.y * q0.y + a.z * q0.z + a.w * q0.w;
        }
        __syncthreads();
    }

    int idx = tid & 63;
    if (ks > 0) red[ks - 1][idx] = acc;
    __syncthreads();
    if (ks == 0) {
        acc += red[0][idx] + red[1][idx] + red[2][idx];
        float o = tanh_(acc);
        feedn[b * H_ + j] = o;
        dout[((size_t)b * T_ + t) * H_ + j] = o;
    }
}

// ---------------------------------------------------------------------------
extern "C" void kernel_launch(void* const* d_in, const int* in_sizes, int n_in,
                              void* d_out, int out_size, void* d_ws, size_t ws_size,
                              hipStream_t stream) {
    const int*   tgt    = (const int*)  d_in[0];
    const float* mem    = (const float*)d_in[1];
    const int*   masks  = (const int*)  d_in[2];
    const float* h0in   = (const float*)d_in[3];
    const float* c0in   = (const float*)d_in[4];
    const float* emb    = (const float*)d_in[5];
    const float* w_ih0  = (const float*)d_in[6];
    const float* w_hh0  = (const float*)d_in[7];
    const float* b_ih0  = (const float*)d_in[8];
    const float* b_hh0  = (const float*)d_in[9];
    const float* w_ih1  = (const float*)d_in[10];
    const float* w_hh1  = (const float*)d_in[11];
    const float* b_ih1  = (const float*)d_in[12];
    const float* b_hh1  = (const float*)d_in[13];
    const float* w_in   = (const float*)d_in[14];
    const float* w_out  = (const float*)d_in[15];

    float* dout     = (float*)d_out;
    float* attn_out = dout + (size_t)B_ * T_ * H_;

    float* ws   = (float*)d_ws;
    float* h0s  = ws;              // [2][B*H]
    float* c0s  = h0s  + 2 * BH_;  // [2][B*H]
    float* h1s  = c0s  + 2 * BH_;  // [2][B*H]
    float* c1s  = h1s  + 2 * BH_;  // [2][B*H]
    float* feed = c1s  + 2 * BH_;  // [2][B*H]
    float* qctx = feed + 2 * BH_;  // [B*H]
    float* scw  = qctx + BH_;      // [B*S]
    float* pmem = scw  + B_ * S_;  // [B*S*H]      33.5 MB
    float* gemb = pmem + (size_t)B_ * S_ * H_;     // [B*T*4096]  33.5 MB
    float* part0 = gemb + (size_t)B_ * T_ * 4096;  // [8][32][4096]  4 MB
    float* part1 = part0 + (size_t)8 * 32 * 4096;  // [8][32][4096]  4 MB
    float* part2 = part1 + (size_t)8 * 32 * 4096;  // [16][32][1024] 2 MB

    const size_t base_fl = (size_t)11 * BH_ + B_ * S_;
    const size_t big_fl  = (size_t)B_ * S_ * H_ + (size_t)B_ * T_ * 4096;
    const size_t part_fl = (size_t)2 * 8 * 32 * 4096 + (size_t)16 * 32 * 1024;
    const size_t needA = (base_fl + big_fl + part_fl) * 4;
    const size_t needB = (base_fl + big_fl) * 4;

    k_init<<<128, 256, 0, stream>>>(h0in, c0in, h0s, c0s, h1s, c1s, feed);

    if (ws_size >= needA) {
        // ---------- tier A: all GEMMs in k_gates tiling ----------
        k_pmem<<<dim3(128, 16), 256, 0, stream>>>(mem, w_in, pmem);
        k_gemb<<<dim3(32, 64), 256, 0, stream>>>(tgt, emb, w_ih0, gemb);

        for (int t = 0; t < T_; ++t) {
            int cur = t & 1, nxt = cur ^ 1;
            k_gates<<<dim3(64, 8), 256, 0, stream>>>(
                feed + cur * BH_, h0s + cur * BH_,
                w_ih0 + 512, 1536, w_hh0, 1024, part0, 4096, 256);
            k_cell<<<128, 256, 0, stream>>>(part0, b_ih0, b_hh0, gemb, 1,
                                            c0s + cur * BH_, c0s + nxt * BH_,
                                            h0s + nxt * BH_, t);
            k_gates<<<dim3(64, 8), 256, 0, stream>>>(
                h0s + nxt * BH_, h1s + cur * BH_,
                w_ih1, 1024, w_hh1, 1024, part1, 4096, 256);
            k_cell<<<128, 256, 0, stream>>>(part1, b_ih1, b_hh1, gemb, 0,
                                            c1s + cur * BH_, c1s + nxt * BH_,
                                            h1s + nxt * BH_, t);
            k_scores<<<512, 256, 0, stream>>>(h1s + nxt * BH_, pmem, scw);
            k_ctx<<<512, 256, 0, stream>>>(scw, mem, masks, qctx, attn_out, t);
            k_gates<<<dim3(16, 16), 256, 0, stream>>>(
                qctx, h1s + nxt * BH_,
                w_out, 2048, w_out + 1024, 2048, part2, 1024, 128);
            k_outcell<<<128, 256, 0, stream>>>(part2, feed + nxt * BH_, dout, t);
        }
    } else if (ws_size >= needB) {
        // ---------- tier B: R13 champion structure ----------
        k_pmem<<<dim3(128, 16), 256, 0, stream>>>(mem, w_in, pmem);
        k_gemb<<<dim3(32, 64), 256, 0, stream>>>(tgt, emb, w_ih0, gemb);

        for (int t = 0; t < T_; ++t) {
            int cur = t & 1, nxt = cur ^ 1;
            k_lstm0<<<512, 256, 0, stream>>>(tgt, emb, w_ih0, w_hh0, b_ih0, b_hh0,
                                             feed + cur * BH_, h0s + cur * BH_, c0s + cur * BH_,
                                             h0s + nxt * BH_, c0s + nxt * BH_, t);
            k_lstm1<<<512, 256, 0, stream>>>(w_ih1, w_hh1, b_ih1, b_hh1,
                                             h0s + nxt * BH_, h1s + cur * BH_, c1s + cur * BH_,
                                             h1s + nxt * BH_, c1s + nxt * BH_);
            k_scores<<<512, 256, 0, stream>>>(h1s + nxt * BH_, pmem, scw);
            k_ctx<<<512, 256, 0, stream>>>(scw, mem, masks, qctx, attn_out, t);
            k_out<<<512, 256, 0, stream>>>(w_out, qctx, h1s + nxt * BH_,
                                           feed + nxt * BH_, dout, t);
        }
    } else {
        // ---------- minimal tier (round-2) ----------
        for (int t = 0; t < T_; ++t) {
            int cur = t & 1, nxt = cur ^ 1;
            k_lstm0<<<512, 256, 0, stream>>>(tgt, emb, w_ih0, w_hh0, b_ih0, b_hh0,
                                             feed + cur * BH_, h0s + cur * BH_, c0s + cur * BH_,
                                             h0s + nxt * BH_, c0s + nxt * BH_, t);
            k_lstm1<<<512, 256, 0, stream>>>(w_ih1, w_hh1, b_ih1, b_hh1,
                                             h0s + nxt * BH_, h1s + cur * BH_, c1s + cur * BH_,
                                             h1s + nxt * BH_, c1s + nxt * BH_);
            k_q<<<512, 256, 0, stream>>>(w_in, h1s + nxt * BH_, qctx);
            k_scores<<<512, 256, 0, stream>>>(qctx, mem, scw);
            k_ctx<<<512, 256, 0, stream>>>(scw, mem, masks, qctx, attn_out, t);
            k_out<<<512, 256, 0, stream>>>(w_out, qctx, h1s + nxt * BH_,
                                           feed + nxt * BH_, dout, t);
        }
    }
}

// Round 16
// 4921.597 us; speedup vs baseline: 1.7924x; 1.0394x over previous
//
#include <hip/hip_runtime.h>
#include <math.h>

#define B_ 32
#define T_ 64
#define S_ 256
#define H_ 1024
#define E_ 512
#define BH_ (B_ * H_)

__device__ __forceinline__ float sigm(float x) {
    return 1.0f / (1.0f + __expf(-x));
}
__device__ __forceinline__ float tanh_(float x) {
    x = fminf(15.0f, fmaxf(-15.0f, x));
    float e = __expf(-2.0f * x);
    return (1.0f - e) / (1.0f + e);
}
// f32 -> bf16 round-to-nearest-even (finite inputs)
__device__ __forceinline__ unsigned short f2bf(float f) {
    unsigned int u = __float_as_uint(f);
    u = (u + 0x7fffu + ((u >> 16) & 1u)) >> 16;
    return (unsigned short)u;
}
__device__ __forceinline__ float bflo(unsigned int u) { return __uint_as_float(u << 16); }
__device__ __forceinline__ float bfhi(unsigned int u) { return __uint_as_float(u & 0xffff0000u); }
__device__ __forceinline__ float bfu(unsigned short u) { return __uint_as_float((unsigned int)u << 16); }

// ---------------------------------------------------------------------------
// init: state ping-pong slot 0 + zero input feed
// ---------------------------------------------------------------------------
__global__ void k_init(const float* __restrict__ h0in, const float* __restrict__ c0in,
                       float* h0s, float* c0s, float* h1s, float* c1s, float* feed) {
    int i = blockIdx.x * 256 + threadIdx.x;
    if (i < BH_) {
        h0s[i]  = h0in[i];
        h1s[i]  = h0in[BH_ + i];
        c0s[i]  = c0in[i];
        c1s[i]  = c0in[BH_ + i];
        feed[i] = 0.0f;
    }
}

// ---------------------------------------------------------------------------
// k_cvtmem: mem f32 -> bf16, 8192 rows of 1024.  grid 8192, block 256.
// ---------------------------------------------------------------------------
__global__ __launch_bounds__(256) void k_cvtmem(
    const float* __restrict__ src, unsigned short* __restrict__ dst)
{
    size_t base = (size_t)blockIdx.x * 1024 + threadIdx.x * 4;
    float4 v = *(const float4*)(src + base);
    ushort4 u;
    u.x = f2bf(v.x); u.y = f2bf(v.y); u.z = f2bf(v.z); u.w = f2bf(v.w);
    *(ushort4*)(dst + base) = u;
}

// ---------------------------------------------------------------------------
// pmem bf16: pmem[r][k] = sum_j mem[r][j] * w_in[j][k]  (R12-proven, 232 µs)
// ---------------------------------------------------------------------------
__global__ __launch_bounds__(256) void k_pmem_bf(
    const float* __restrict__ mem, const float* __restrict__ w_in,
    unsigned short* __restrict__ pmem)
{
    __shared__ float As[64][36];
    __shared__ float Bs[32][68];

    const int tid = threadIdx.x;
    const int rt = blockIdx.x * 64;
    const int ct = blockIdx.y * 64;
    const int tx = tid & 15;
    const int ty = tid >> 4;

    float acc[4][4] = {{0.f}};

    for (int jc = 0; jc < 1024; jc += 32) {
        #pragma unroll
        for (int i = 0; i < 2; ++i) {
            int s2  = tid + i * 256;
            int row = s2 >> 3, kq = s2 & 7;
            *(float4*)&As[row][kq * 4] =
                *(const float4*)(mem + (size_t)(rt + row) * 1024 + jc + kq * 4);
        }
        #pragma unroll
        for (int i = 0; i < 2; ++i) {
            int s2 = tid + i * 256;
            int kk = s2 >> 4, cq = s2 & 15;
            *(float4*)&Bs[kk][cq * 4] =
                *(const float4*)(w_in + (size_t)(jc + kk) * 1024 + ct + cq * 4);
        }
        __syncthreads();

        #pragma unroll
        for (int kk = 0; kk < 32; ++kk) {
            float a0 = As[ty * 4 + 0][kk], a1 = As[ty * 4 + 1][kk];
            float a2 = As[ty * 4 + 2][kk], a3 = As[ty * 4 + 3][kk];
            float b0 = Bs[kk][tx * 4 + 0], b1 = Bs[kk][tx * 4 + 1];
            float b2 = Bs[kk][tx * 4 + 2], b3 = Bs[kk][tx * 4 + 3];
            acc[0][0] += a0 * b0; acc[0][1] += a0 * b1; acc[0][2] += a0 * b2; acc[0][3] += a0 * b3;
            acc[1][0] += a1 * b0; acc[1][1] += a1 * b1; acc[1][2] += a1 * b2; acc[1][3] += a1 * b3;
            acc[2][0] += a2 * b0; acc[2][1] += a2 * b1; acc[2][2] += a2 * b2; acc[2][3] += a2 * b3;
            acc[3][0] += a3 * b0; acc[3][1] += a3 * b1; acc[3][2] += a3 * b2; acc[3][3] += a3 * b3;
        }
        __syncthreads();
    }

    #pragma unroll
    for (int i = 0; i < 4; ++i) {
        ushort4 u;
        u.x = f2bf(acc[i][0]); u.y = f2bf(acc[i][1]);
        u.z = f2bf(acc[i][2]); u.w = f2bf(acc[i][3]);
        *(ushort4*)(pmem + (size_t)(rt + ty * 4 + i) * 1024 + ct + tx * 4) = u;
    }
}

// ---------------------------------------------------------------------------
// pmem f32 (tier-B fallback)
// ---------------------------------------------------------------------------
__global__ __launch_bounds__(256) void k_pmem(
    const float* __restrict__ mem, const float* __restrict__ w_in,
    float* __restrict__ pmem)
{
    __shared__ float As[64][36];
    __shared__ float Bs[32][68];

    const int tid = threadIdx.x;
    const int rt = blockIdx.x * 64;
    const int ct = blockIdx.y * 64;
    const int tx = tid & 15;
    const int ty = tid >> 4;

    float acc[4][4] = {{0.f}};

    for (int jc = 0; jc < 1024; jc += 32) {
        #pragma unroll
        for (int i = 0; i < 2; ++i) {
            int s2  = tid + i * 256;
            int row = s2 >> 3, kq = s2 & 7;
            *(float4*)&As[row][kq * 4] =
                *(const float4*)(mem + (size_t)(rt + row) * 1024 + jc + kq * 4);
        }
        #pragma unroll
        for (int i = 0; i < 2; ++i) {
            int s2 = tid + i * 256;
            int kk = s2 >> 4, cq = s2 & 15;
            *(float4*)&Bs[kk][cq * 4] =
                *(const float4*)(w_in + (size_t)(jc + kk) * 1024 + ct + cq * 4);
        }
        __syncthreads();

        #pragma unroll
        for (int kk = 0; kk < 32; ++kk) {
            float a0 = As[ty * 4 + 0][kk], a1 = As[ty * 4 + 1][kk];
            float a2 = As[ty * 4 + 2][kk], a3 = As[ty * 4 + 3][kk];
            float b0 = Bs[kk][tx * 4 + 0], b1 = Bs[kk][tx * 4 + 1];
            float b2 = Bs[kk][tx * 4 + 2], b3 = Bs[kk][tx * 4 + 3];
            acc[0][0] += a0 * b0; acc[0][1] += a0 * b1; acc[0][2] += a0 * b2; acc[0][3] += a0 * b3;
            acc[1][0] += a1 * b0; acc[1][1] += a1 * b1; acc[1][2] += a1 * b2; acc[1][3] += a1 * b3;
            acc[2][0] += a2 * b0; acc[2][1] += a2 * b1; acc[2][2] += a2 * b2; acc[2][3] += a2 * b3;
            acc[3][0] += a3 * b0; acc[3][1] += a3 * b1; acc[3][2] += a3 * b2; acc[3][3] += a3 * b3;
        }
        __syncthreads();
    }

    #pragma unroll
    for (int i = 0; i < 4; ++i) {
        float4 v = make_float4(acc[i][0], acc[i][1], acc[i][2], acc[i][3]);
        *(float4*)(pmem + (size_t)(rt + ty * 4 + i) * 1024 + ct + tx * 4) = v;
    }
}

// ---------------------------------------------------------------------------
// gemb[r][n] = sum_k emb[tgt[r]][k] * w_ih0[n][k]   (r = b*64+t; K = 512)
// ---------------------------------------------------------------------------
__global__ __launch_bounds__(256) void k_gemb(
    const int* __restrict__ tgt, const float* __restrict__ emb,
    const float* __restrict__ w_ih0, float* __restrict__ gemb)
{
    __shared__ float As[64][36];
    __shared__ float Bs[64][37];
    __shared__ int   tok_s[64];

    const int tid = threadIdx.x;
    const int rt = blockIdx.x * 64;
    const int ct = blockIdx.y * 64;
    const int tx = tid & 15;
    const int ty = tid >> 4;

    if (tid < 64) tok_s[tid] = tgt[rt + tid];
    __syncthreads();

    float acc[4][4] = {{0.f}};

    for (int jc = 0; jc < 512; jc += 32) {
        #pragma unroll
        for (int i = 0; i < 2; ++i) {
            int s2  = tid + i * 256;
            int row = s2 >> 3, kq = s2 & 7;
            *(float4*)&As[row][kq * 4] =
                *(const float4*)(emb + (size_t)tok_s[row] * E_ + jc + kq * 4);
        }
        #pragma unroll
        for (int i = 0; i < 2; ++i) {
            int s2 = tid + i * 256;
            int n  = s2 >> 3, kq = s2 & 7;
            *(float4*)&Bs[n][kq * 4] =
                *(const float4*)(w_ih0 + (size_t)(ct + n) * 1536 + jc + kq * 4);
        }
        __syncthreads();

        #pragma unroll
        for (int kk = 0; kk < 32; ++kk) {
            float a0 = As[ty * 4 + 0][kk], a1 = As[ty * 4 + 1][kk];
            float a2 = As[ty * 4 + 2][kk], a3 = As[ty * 4 + 3][kk];
            float b0 = Bs[tx * 4 + 0][kk], b1 = Bs[tx * 4 + 1][kk];
            float b2 = Bs[tx * 4 + 2][kk], b3 = Bs[tx * 4 + 3][kk];
            acc[0][0] += a0 * b0; acc[0][1] += a0 * b1; acc[0][2] += a0 * b2; acc[0][3] += a0 * b3;
            acc[1][0] += a1 * b0; acc[1][1] += a1 * b1; acc[1][2] += a1 * b2; acc[1][3] += a1 * b3;
            acc[2][0] += a2 * b0; acc[2][1] += a2 * b1; acc[2][2] += a2 * b2; acc[2][3] += a2 * b3;
            acc[3][0] += a3 * b0; acc[3][1] += a3 * b1; acc[3][2] += a3 * b2; acc[3][3] += a3 * b3;
        }
        __syncthreads();
    }

    #pragma unroll
    for (int i = 0; i < 4; ++i) {
        float4 v = make_float4(acc[i][0], acc[i][1], acc[i][2], acc[i][3]);
        *(float4*)(gemb + (size_t)(rt + ty * 4 + i) * 4096 + ct + tx * 4) = v;
    }
}

// ---------------------------------------------------------------------------
// k_gates (R14-proven): part[ks][b][nstride] = partial GEMM over K-slice
// ---------------------------------------------------------------------------
__global__ __launch_bounds__(256) void k_gates(
    const float* __restrict__ a0, const float* __restrict__ a1,
    const float* __restrict__ wa, int lda,
    const float* __restrict__ wb, int ldb,
    float* __restrict__ part, int nstride, int kslice)
{
    __shared__ float As[32][33];
    __shared__ float Bs[64][33];

    const int tid = threadIdx.x;
    const int nt = blockIdx.x;
    const int ks = blockIdx.y;
    const int tx = tid & 15;
    const int ty = tid >> 4;

    const int k0 = ks * kslice;
    const bool hi = (k0 >= 1024);
    const float* a   = hi ? a1 : a0;
    const float* w   = hi ? wb : wa;
    const int    ldw = hi ? ldb : lda;
    const int    ko  = hi ? (k0 - 1024) : k0;
    const int    nchunks = kslice >> 5;

    float acc[2][4] = {{0.f, 0.f, 0.f, 0.f}, {0.f, 0.f, 0.f, 0.f}};

    for (int c = 0; c < nchunks; ++c) {
        {
            int row = tid >> 3, kq = tid & 7;
            float4 v = *(const float4*)(a + (size_t)row * H_ + ko + c * 32 + kq * 4);
            As[row][kq * 4 + 0] = v.x; As[row][kq * 4 + 1] = v.y;
            As[row][kq * 4 + 2] = v.z; As[row][kq * 4 + 3] = v.w;
        }
        #pragma unroll
        for (int i = 0; i < 2; ++i) {
            int s2 = tid + i * 256;
            int n = s2 >> 3, kq = s2 & 7;
            float4 v = *(const float4*)(w + (size_t)(nt * 64 + n) * ldw + ko + c * 32 + kq * 4);
            Bs[n][kq * 4 + 0] = v.x; Bs[n][kq * 4 + 1] = v.y;
            Bs[n][kq * 4 + 2] = v.z; Bs[n][kq * 4 + 3] = v.w;
        }
        __syncthreads();

        #pragma unroll
        for (int kk = 0; kk < 32; ++kk) {
            float av0 = As[ty * 2 + 0][kk];
            float av1 = As[ty * 2 + 1][kk];
            float b0 = Bs[tx * 4 + 0][kk], b1 = Bs[tx * 4 + 1][kk];
            float b2 = Bs[tx * 4 + 2][kk], b3 = Bs[tx * 4 + 3][kk];
            acc[0][0] += av0 * b0; acc[0][1] += av0 * b1;
            acc[0][2] += av0 * b2; acc[0][3] += av0 * b3;
            acc[1][0] += av1 * b0; acc[1][1] += av1 * b1;
            acc[1][2] += av1 * b2; acc[1][3] += av1 * b3;
        }
        __syncthreads();
    }

    #pragma unroll
    for (int r = 0; r < 2; ++r) {
        int b = ty * 2 + r;
        float4 v = make_float4(acc[r][0], acc[r][1], acc[r][2], acc[r][3]);
        *(float4*)(part + ((size_t)ks * 32 + b) * nstride + nt * 64 + tx * 4) = v;
    }
}

// ---------------------------------------------------------------------------
// k_cell: sum 8 k-split partials + biases (+ gemb), apply LSTM cell.
// ---------------------------------------------------------------------------
__global__ __launch_bounds__(256) void k_cell(
    const float* __restrict__ part,
    const float* __restrict__ b_ih, const float* __restrict__ b_hh,
    const float* __restrict__ ge, int has_ge,
    const float* __restrict__ c_cur, float* __restrict__ c_nxt,
    float* __restrict__ h_nxt, int t)
{
    int idx = blockIdx.x * 256 + threadIdx.x;
    int b = idx >> 10;
    int j = idx & 1023;

    float g0 = b_ih[0 * H_ + j] + b_hh[0 * H_ + j];
    float g1 = b_ih[1 * H_ + j] + b_hh[1 * H_ + j];
    float g2 = b_ih[2 * H_ + j] + b_hh[2 * H_ + j];
    float g3 = b_ih[3 * H_ + j] + b_hh[3 * H_ + j];
    if (has_ge) {
        const float* g = ge + ((size_t)b * 64 + t) * 4096;
        g0 += g[0 * H_ + j]; g1 += g[1 * H_ + j];
        g2 += g[2 * H_ + j]; g3 += g[3 * H_ + j];
    }
    #pragma unroll
    for (int p = 0; p < 8; ++p) {
        const float* pp = part + ((size_t)p * 32 + b) * 4096;
        g0 += pp[0 * H_ + j]; g1 += pp[1 * H_ + j];
        g2 += pp[2 * H_ + j]; g3 += pp[3 * H_ + j];
    }
    float co = c_cur[b * H_ + j];
    float cn = sigm(g1) * co + sigm(g0) * tanh_(g2);
    c_nxt[b * H_ + j] = cn;
    h_nxt[b * H_ + j] = sigm(g3) * tanh_(cn);
}

// ---------------------------------------------------------------------------
// k_outcell: sum 16 k-split partials, tanh, write feed_next + dout[:, t]
// ---------------------------------------------------------------------------
__global__ __launch_bounds__(256) void k_outcell(
    const float* __restrict__ part,
    float* __restrict__ feedn, float* __restrict__ dout, int t)
{
    int idx = blockIdx.x * 256 + threadIdx.x;
    int b = idx >> 10;
    int j = idx & 1023;

    float g = 0.0f;
    #pragma unroll
    for (int p = 0; p < 16; ++p)
        g += part[((size_t)p * 32 + b) * 1024 + j];

    float o = tanh_(g);
    feedn[b * H_ + j] = o;
    dout[((size_t)b * T_ + t) * H_ + j] = o;
}

// ---------------------------------------------------------------------------
// scores vs bf16 pmem (R12-proven): scores[b][s] = h1[b] . pmem[b][s]
// ---------------------------------------------------------------------------
__global__ __launch_bounds__(256) void k_scores_bf(
    const float* __restrict__ x_in, const unsigned short* __restrict__ base,
    float* __restrict__ sc_out)
{
    __shared__ float q_lds[1024];

    int b  = blockIdx.x >> 4;
    int st = blockIdx.x & 15;
    int tid  = threadIdx.x;
    int lane = tid & 63;
    int wv   = tid >> 6;

    ((float4*)q_lds)[tid] = ((const float4*)(x_in + (size_t)b * H_))[tid];
    __syncthreads();

    float4 qa[2][2];
    #pragma unroll
    for (int i = 0; i < 2; ++i) {
        int u = lane + 64 * i;
        qa[i][0] = ((const float4*)q_lds)[2 * u];
        qa[i][1] = ((const float4*)q_lds)[2 * u + 1];
    }

    const unsigned short* mb = base + (size_t)b * S_ * H_;
    #pragma unroll
    for (int ss = 0; ss < 4; ++ss) {
        int s = st * 16 + wv * 4 + ss;
        const uint4* mr = (const uint4*)(mb + (size_t)s * H_);
        float a = 0.0f;
        #pragma unroll
        for (int i = 0; i < 2; ++i) {
            uint4 m = mr[lane + 64 * i];
            float4 lo = qa[i][0], hi = qa[i][1];
            a += lo.x*bflo(m.x)+lo.y*bfhi(m.x)+lo.z*bflo(m.y)+lo.w*bfhi(m.y)
               + hi.x*bflo(m.z)+hi.y*bfhi(m.z)+hi.z*bflo(m.w)+hi.w*bfhi(m.w);
        }
        #pragma unroll
        for (int o = 32; o > 0; o >>= 1) a += __shfl_down(a, o);
        if (lane == 0) sc_out[b * S_ + s] = a;
    }
}

// ---------------------------------------------------------------------------
// k_scores f32 (tier-B fallback)
// ---------------------------------------------------------------------------
__global__ __launch_bounds__(256) void k_scores(
    const float* __restrict__ x_in, const float* __restrict__ base,
    float* __restrict__ sc_out)
{
    __shared__ float q_lds[1024];

    int b  = blockIdx.x >> 4;
    int st = blockIdx.x & 15;
    int tid  = threadIdx.x;
    int lane = tid & 63;
    int wv   = tid >> 6;

    ((float4*)q_lds)[tid] = ((const float4*)(x_in + (size_t)b * H_))[tid];
    __syncthreads();

    float4 q4[4];
    #pragma unroll
    for (int i = 0; i < 4; ++i) q4[i] = ((const float4*)q_lds)[lane + 64 * i];

    const float* mb = base + (size_t)b * S_ * H_;
    #pragma unroll
    for (int ss = 0; ss < 4; ++ss) {
        int s = st * 16 + wv * 4 + ss;
        const float4* mr = (const float4*)(mb + (size_t)s * H_);
        float a = 0.0f;
        #pragma unroll
        for (int i = 0; i < 4; ++i) {
            float4 m = mr[lane + 64 * i];
            a += q4[i].x * m.x + q4[i].y * m.y + q4[i].z * m.z + q4[i].w * m.w;
        }
        #pragma unroll
        for (int o = 32; o > 0; o >>= 1) a += __shfl_down(a, o);
        if (lane == 0) sc_out[b * S_ + s] = a;
    }
}

// ---------------------------------------------------------------------------
// ctx from bf16 mem: local masked softmax (f32 scores) + weighted sum (bf16)
// ---------------------------------------------------------------------------
__global__ __launch_bounds__(256) void k_ctx_bf(
    const float* __restrict__ sc_in, const unsigned short* __restrict__ memb,
    const int* __restrict__ masks,
    float* __restrict__ ctx, float* __restrict__ attn_out, int t)
{
    __shared__ float aw[256];
    __shared__ float red2[4][64];

    int b  = blockIdx.x >> 4;
    int ht = blockIdx.x & 15;
    int tid  = threadIdx.x;
    int lane = tid & 63;
    int wv   = tid >> 6;

    if (wv == 0) {
        int m = 0;
        #pragma unroll
        for (int i = 0; i < 4; ++i) m += masks[b * S_ + lane * 4 + i];
        #pragma unroll
        for (int o = 32; o > 0; o >>= 1) m += __shfl_down(m, o);
        int len = __shfl(m, 0);

        float v[4];
        float mx = -1e30f;
        #pragma unroll
        for (int i = 0; i < 4; ++i) {
            int s = lane + 64 * i;
            float xv = (s < len) ? sc_in[b * S_ + s] : -1e9f;
            v[i] = xv;
            mx = fmaxf(mx, xv);
        }
        #pragma unroll
        for (int o = 32; o > 0; o >>= 1) mx = fmaxf(mx, __shfl_xor(mx, o));
        float sm = 0.0f;
        #pragma unroll
        for (int i = 0; i < 4; ++i) { v[i] = __expf(v[i] - mx); sm += v[i]; }
        #pragma unroll
        for (int o = 32; o > 0; o >>= 1) sm += __shfl_xor(sm, o);
        float inv = 1.0f / sm;
        #pragma unroll
        for (int i = 0; i < 4; ++i) {
            int s = lane + 64 * i;
            float w = v[i] * inv;
            aw[s] = w;
            if (ht == 0) attn_out[((size_t)b * T_ + t) * S_ + s] = w;
        }
    }
    __syncthreads();

    int h = ht * 64 + lane;
    const unsigned short* mb = memb + (size_t)b * S_ * H_;
    float a = 0.0f;
    #pragma unroll 8
    for (int ss = 0; ss < 64; ++ss) {
        int s = wv * 64 + ss;
        a += aw[s] * bfu(mb[(size_t)s * H_ + h]);
    }
    red2[wv][lane] = a;
    __syncthreads();
    if (tid < 64) {
        float r = red2[0][tid] + red2[1][tid] + red2[2][tid] + red2[3][tid];
        ctx[b * H_ + ht * 64 + tid] = r;
    }
}

// ---------------------------------------------------------------------------
// k_ctx f32 (tier-B fallback)
// ---------------------------------------------------------------------------
__global__ __launch_bounds__(256) void k_ctx(
    const float* __restrict__ sc_in, const float* __restrict__ mem,
    const int* __restrict__ masks,
    float* __restrict__ ctx, float* __restrict__ attn_out, int t)
{
    __shared__ float aw[256];
    __shared__ float red2[4][64];

    int b  = blockIdx.x >> 4;
    int ht = blockIdx.x & 15;
    int tid  = threadIdx.x;
    int lane = tid & 63;
    int wv   = tid >> 6;

    if (wv == 0) {
        int m = 0;
        #pragma unroll
        for (int i = 0; i < 4; ++i) m += masks[b * S_ + lane * 4 + i];
        #pragma unroll
        for (int o = 32; o > 0; o >>= 1) m += __shfl_down(m, o);
        int len = __shfl(m, 0);

        float v[4];
        float mx = -1e30f;
        #pragma unroll
        for (int i = 0; i < 4; ++i) {
            int s = lane + 64 * i;
            float xv = (s < len) ? sc_in[b * S_ + s] : -1e9f;
            v[i] = xv;
            mx = fmaxf(mx, xv);
        }
        #pragma unroll
        for (int o = 32; o > 0; o >>= 1) mx = fmaxf(mx, __shfl_xor(mx, o));
        float sm = 0.0f;
        #pragma unroll
        for (int i = 0; i < 4; ++i) { v[i] = __expf(v[i] - mx); sm += v[i]; }
        #pragma unroll
        for (int o = 32; o > 0; o >>= 1) sm += __shfl_xor(sm, o);
        float inv = 1.0f / sm;
        #pragma unroll
        for (int i = 0; i < 4; ++i) {
            int s = lane + 64 * i;
            float w = v[i] * inv;
            aw[s] = w;
            if (ht == 0) attn_out[((size_t)b * T_ + t) * S_ + s] = w;
        }
    }
    __syncthreads();

    int h = ht * 64 + lane;
    const float* mb = mem + (size_t)b * S_ * H_;
    float a = 0.0f;
    #pragma unroll 8
    for (int ss = 0; ss < 64; ++ss) {
        int s = wv * 64 + ss;
        a += aw[s] * mb[(size_t)s * H_ + h];
    }
    red2[wv][lane] = a;
    __syncthreads();
    if (tid < 64) {
        float r = red2[0][tid] + red2[1][tid] + red2[2][tid] + red2[3][tid];
        ctx[b * H_ + ht * 64 + tid] = r;
    }
}

// ---------------------------------------------------------------------------
extern "C" void kernel_launch(void* const* d_in, const int* in_sizes, int n_in,
                              void* d_out, int out_size, void* d_ws, size_t ws_size,
                              hipStream_t stream) {
    const int*   tgt    = (const int*)  d_in[0];
    const float* mem    = (const float*)d_in[1];
    const int*   masks  = (const int*)  d_in[2];
    const float* h0in   = (const float*)d_in[3];
    const float* c0in   = (const float*)d_in[4];
    const float* emb    = (const float*)d_in[5];
    const float* w_ih0  = (const float*)d_in[6];
    const float* w_hh0  = (const float*)d_in[7];
    const float* b_ih0  = (const float*)d_in[8];
    const float* b_hh0  = (const float*)d_in[9];
    const float* w_ih1  = (const float*)d_in[10];
    const float* w_hh1  = (const float*)d_in[11];
    const float* b_ih1  = (const float*)d_in[12];
    const float* b_hh1  = (const float*)d_in[13];
    const float* w_in   = (const float*)d_in[14];
    const float* w_out  = (const float*)d_in[15];

    float* dout     = (float*)d_out;
    float* attn_out = dout + (size_t)B_ * T_ * H_;

    float* ws   = (float*)d_ws;
    float* h0s  = ws;              // [2][B*H]
    float* c0s  = h0s  + 2 * BH_;  // [2][B*H]
    float* h1s  = c0s  + 2 * BH_;  // [2][B*H]
    float* c1s  = h1s  + 2 * BH_;  // [2][B*H]
    float* feed = c1s  + 2 * BH_;  // [2][B*H]
    float* qctx = feed + 2 * BH_;  // [B*H]
    float* scw  = qctx + BH_;      // [B*S]
    float* gemb = scw  + B_ * S_;                   // [B*T*4096]  33.5 MB
    float* part0 = gemb + (size_t)B_ * T_ * 4096;   // [8][32][4096]  4 MB
    float* part1 = part0 + (size_t)8 * 32 * 4096;   // [8][32][4096]  4 MB
    float* part2 = part1 + (size_t)8 * 32 * 4096;   // [16][32][1024] 2 MB
    // bf16 region (tier A) / f32 pmem (tier B) share this space:
    float* after_parts = part2 + (size_t)16 * 32 * 1024;
    unsigned short* pmb  = (unsigned short*)after_parts;          // 16.8 MB
    unsigned short* memb = pmb + (size_t)B_ * S_ * H_;            // 16.8 MB
    float* pmem_f32 = after_parts;                                // 33.5 MB (tier B)

    const size_t base_fl = (size_t)11 * BH_ + B_ * S_;
    const size_t gemb_fl = (size_t)B_ * T_ * 4096;
    const size_t part_fl = (size_t)2 * 8 * 32 * 4096 + (size_t)16 * 32 * 1024;
    const size_t bf_bytes = (size_t)2 * B_ * S_ * H_ * 2;        // pmb + memb
    const size_t needA = (base_fl + gemb_fl + part_fl) * 4 + bf_bytes;
    const size_t needB = (base_fl + gemb_fl + part_fl + (size_t)B_ * S_ * H_) * 4;

    k_init<<<128, 256, 0, stream>>>(h0in, c0in, h0s, c0s, h1s, c1s, feed);

    if (ws_size >= needA) {
        // ---------- tier A: k_gates GEMMs + bf16 attention streams ----------
        k_pmem_bf<<<dim3(128, 16), 256, 0, stream>>>(mem, w_in, pmb);
        k_gemb<<<dim3(32, 64), 256, 0, stream>>>(tgt, emb, w_ih0, gemb);
        k_cvtmem<<<8192, 256, 0, stream>>>(mem, memb);

        for (int t = 0; t < T_; ++t) {
            int cur = t & 1, nxt = cur ^ 1;
            k_gates<<<dim3(64, 8), 256, 0, stream>>>(
                feed + cur * BH_, h0s + cur * BH_,
                w_ih0 + 512, 1536, w_hh0, 1024, part0, 4096, 256);
            k_cell<<<128, 256, 0, stream>>>(part0, b_ih0, b_hh0, gemb, 1,
                                            c0s + cur * BH_, c0s + nxt * BH_,
                                            h0s + nxt * BH_, t);
            k_gates<<<dim3(64, 8), 256, 0, stream>>>(
                h0s + nxt * BH_, h1s + cur * BH_,
                w_ih1, 1024, w_hh1, 1024, part1, 4096, 256);
            k_cell<<<128, 256, 0, stream>>>(part1, b_ih1, b_hh1, gemb, 0,
                                            c1s + cur * BH_, c1s + nxt * BH_,
                                            h1s + nxt * BH_, t);
            k_scores_bf<<<512, 256, 0, stream>>>(h1s + nxt * BH_, pmb, scw);
            k_ctx_bf<<<512, 256, 0, stream>>>(scw, memb, masks, qctx, attn_out, t);
            k_gates<<<dim3(16, 16), 256, 0, stream>>>(
                qctx, h1s + nxt * BH_,
                w_out, 2048, w_out + 1024, 2048, part2, 1024, 128);
            k_outcell<<<128, 256, 0, stream>>>(part2, feed + nxt * BH_, dout, t);
        }
    } else if (ws_size >= needB) {
        // ---------- tier B: R15 champion (full f32) ----------
        k_pmem<<<dim3(128, 16), 256, 0, stream>>>(mem, w_in, pmem_f32);
        k_gemb<<<dim3(32, 64), 256, 0, stream>>>(tgt, emb, w_ih0, gemb);

        for (int t = 0; t < T_; ++t) {
            int cur = t & 1, nxt = cur ^ 1;
            k_gates<<<dim3(64, 8), 256, 0, stream>>>(
                feed + cur * BH_, h0s + cur * BH_,
                w_ih0 + 512, 1536, w_hh0, 1024, part0, 4096, 256);
            k_cell<<<128, 256, 0, stream>>>(part0, b_ih0, b_hh0, gemb, 1,
                                            c0s + cur * BH_, c0s + nxt * BH_,
                                            h0s + nxt * BH_, t);
            k_gates<<<dim3(64, 8), 256, 0, stream>>>(
                h0s + nxt * BH_, h1s + cur * BH_,
                w_ih1, 1024, w_hh1, 1024, part1, 4096, 256);
            k_cell<<<128, 256, 0, stream>>>(part1, b_ih1, b_hh1, gemb, 0,
                                            c1s + cur * BH_, c1s + nxt * BH_,
                                            h1s + nxt * BH_, t);
            k_scores<<<512, 256, 0, stream>>>(h1s + nxt * BH_, pmem_f32, scw);
            k_ctx<<<512, 256, 0, stream>>>(scw, mem, masks, qctx, attn_out, t);
            k_gates<<<dim3(16, 16), 256, 0, stream>>>(
                qctx, h1s + nxt * BH_,
                w_out, 2048, w_out + 1024, 2048, part2, 1024, 128);
            k_outcell<<<128, 256, 0, stream>>>(part2, feed + nxt * BH_, dout, t);
        }
    }
}